// Round 17
// baseline (162.537 us; speedup 1.0000x reference)
//
#include <hip/hip_runtime.h>
#include <hip/hip_bf16.h>

#define NN 50000
#define NE 800000
#define NBKT 196        // ceil(NN/256) buckets of 256 nodes
#define NT 200          // partition tiles
#define TILE 4000       // NE/NT exactly

typedef unsigned short ushort_t;
typedef unsigned int uint_t;
typedef signed char s8_t;

typedef __bf16 bf16_t;
typedef bf16_t bf16x8 __attribute__((ext_vector_type(8)));
typedef float f32x4 __attribute__((ext_vector_type(4)));

__device__ __forceinline__ float leaky(float v) { return (v >= 0.f) ? v : 0.2f * v; }
__device__ __forceinline__ ushort_t f2bf(float f) {
    __hip_bfloat16 h = __float2bfloat16(f);
    return *reinterpret_cast<ushort_t*>(&h);
}
__device__ __forceinline__ float bf_lo(uint_t v) { return __uint_as_float(v << 16); }
__device__ __forceinline__ float bf_hi(uint_t v) { return __uint_as_float(v & 0xFFFF0000u); }

// ---------------- prep + hist ----------------

#define WELEM (128 * 64 * 3)
#define WBLK 96

__global__ void prep_hist(const float* __restrict__ W1, const float* __restrict__ W2,
                          const float* __restrict__ W3, ushort_t* __restrict__ Wt1,
                          ushort_t* __restrict__ Wt2, ushort_t* __restrict__ Wt3,
                          const float* __restrict__ al2, const float* __restrict__ ar2,
                          float* __restrict__ val2, float* __restrict__ var2,
                          const int* __restrict__ dst, uint_t* __restrict__ gh) {
    __shared__ uint_t h[NBKT];
    int tid = threadIdx.x;
    int blk = blockIdx.x;
    if (blk < NT) {  // histogram tile
        for (int i = tid; i < NBKT; i += 256) h[i] = 0;
        __syncthreads();
        int e0 = blk * TILE;
        for (int i = tid; i < TILE; i += 256)
            atomicAdd(&h[((uint_t)dst[e0 + i]) >> 8], 1u);
        __syncthreads();
        for (int i = tid; i < NBKT; i += 256) gh[(size_t)i * NT + blk] = h[i];
        return;
    }
    blk -= NT;
    if (blk < WBLK) {  // weights -> bf16^T, 1 elem/thread
        int gw = blk * 256 + tid;
        if (gw < 128 * 64) {
            int i = gw; int k = i >> 6, m = i & 63;
            Wt1[m * 128 + k] = f2bf(W1[i]);
        } else if (gw < 2 * 128 * 64) {
            int i = gw - 128 * 64; int k = i >> 7, m = i & 127;
            Wt2[m * 64 + k] = f2bf(W2[i]);
        } else if (gw < WELEM) {
            int i = gw - 2 * 128 * 64; int k = i >> 6, m = i & 63;
            Wt3[m * 128 + k] = f2bf(W3[i]);
        }
        return;
    }
    // last block: layer-2 attention vectors
    if (tid < 128) {
        int k = tid & 63;
        const float* av = (tid < 64) ? al2 : ar2;
        float acc = 0.f;
        const float* row = W2 + k * 128;
        #pragma unroll 8
        for (int m = 0; m < 128; ++m) acc += row[m] * av[m];
        if (tid < 64) val2[k] = acc; else var2[k] = acc;
    }
}

// ---------------- scan: wave-per-bucket over tiles ----------------
__global__ void scan_gh(uint_t* __restrict__ gh, uint_t* __restrict__ bucketbase) {
    __shared__ uint_t btot[NBKT];
    __shared__ uint_t ws4[4];
    int tid = threadIdx.x;          // 1024 threads, 16 waves
    int wv = tid >> 6, lane = tid & 63;
    for (int b = wv; b < NBKT; b += 16) {
        uint_t* row = gh + (size_t)b * NT;
        uint_t carry = 0;
        for (int base = 0; base < NT; base += 64) {
            int idx = base + lane;
            uint_t v = (idx < NT) ? row[idx] : 0;
            uint_t sc = v;
            for (int o = 1; o < 64; o <<= 1) {
                uint_t xx = __shfl_up(sc, o);
                if (lane >= o) sc += xx;
            }
            if (idx < NT) row[idx] = carry + sc - v;
            carry += __shfl(sc, 63);
        }
        if (lane == 0) btot[b] = carry;
    }
    __syncthreads();
    uint_t v = 0, sc = 0;
    if (tid < 256) {
        v = (tid < NBKT) ? btot[tid] : 0;
        sc = v;
        for (int o = 1; o < 64; o <<= 1) {
            uint_t xx = __shfl_up(sc, o);
            if ((tid & 63) >= o) sc += xx;
        }
        if ((tid & 63) == 63) ws4[tid >> 6] = sc;
    }
    __syncthreads();
    if (tid == 0) {
        uint_t r = 0;
        for (int i = 0; i < 4; ++i) { uint_t tmp = ws4[i]; ws4[i] = r; r += tmp; }
    }
    __syncthreads();
    if (tid < NBKT) bucketbase[tid] = ws4[tid >> 6] + sc - v;
    if (tid == 0) bucketbase[NBKT] = NE;
}

__global__ void part_scatter(const int* __restrict__ src, const int* __restrict__ dst,
                             const uint_t* __restrict__ gh, const uint_t* __restrict__ bucketbase,
                             uint_t* __restrict__ pairbuf) {
    __shared__ uint_t cur[NBKT];
    int t = blockIdx.x, tid = threadIdx.x;
    for (int i = tid; i < NBKT; i += 256)
        cur[i] = gh[(size_t)i * NT + t] + bucketbase[i];
    __syncthreads();
    int e0 = t * TILE;
    for (int i = tid; i < TILE; i += 256) {
        int d = dst[e0 + i], s = src[e0 + i];
        uint_t pos = atomicAdd(&cur[((uint_t)d) >> 8], 1u);
        pairbuf[pos] = (uint_t)s | (((uint_t)d & 255u) << 16);
    }
}

// ---------------- agg core with PAIRED gather: 2 edge-rows per wave-instruction -------
// lanes 0-15: even edge, cols 4q..4q+3; lanes 16-31: odd edge, same cols. One
// shfl_xor(16) folds halves. Returns alpha-weighted sums (valid, duplicated, on all 32).
// INFMT 0: int8 64B rows + packed {el,scl}; INFMT 1: bf16 128B rows + plain el.
template <int INFMT>
__device__ __forceinline__ float4 agg_node(const int* __restrict__ off,
                                           const int* __restrict__ csrsrc,
                                           const float2* __restrict__ elscl,
                                           const float* __restrict__ elp,
                                           const float* __restrict__ er,
                                           const void* __restrict__ featv,
                                           int node, int sub) {
    int start = off[node], deg = off[node + 1] - start;
    float ern = er[node];

    int s0 = 0; float e0 = -1e30f; float sc0 = 0.f;
    if (sub < deg) {
        s0 = csrsrc[start + sub];
        if (INFMT == 0) { float2 es = elscl[s0]; e0 = leaky(es.x + ern); sc0 = es.y; }
        else            { e0 = leaky(elp[s0] + ern); }
    }
    float m = e0;
    for (int i = 32 + sub; i < deg; i += 32) {
        int s = csrsrc[start + i];
        float ev = (INFMT == 0) ? elscl[s].x : elp[s];
        m = fmaxf(m, leaky(ev + ern));
    }
    for (int o = 16; o; o >>= 1) m = fmaxf(m, __shfl_xor(m, o));

    float p0 = (sub < deg) ? __expf(e0 - m) : 0.f;
    float ssum = p0;
    for (int i = 32 + sub; i < deg; i += 32) {
        int s = csrsrc[start + i];
        float ev = (INFMT == 0) ? elscl[s].x : elp[s];
        ssum += __expf(leaky(ev + ern) - m);
    }
    for (int o = 16; o; o >>= 1) ssum += __shfl_xor(ssum, o);
    float inv = (deg > 0) ? 1.f / ssum : 0.f;

    float ps0 = (INFMT == 0) ? p0 * sc0 : p0;

    int half = sub >> 4, q = sub & 15;
    float a0 = 0.f, a1 = 0.f, a2 = 0.f, a3 = 0.f;

    #define GATHER_PAIR(sA_, pA_, sB_, pB_)                                            \
    {                                                                                  \
        int sM = half ? (sB_) : (sA_); float pM = half ? (pB_) : (pA_);                \
        if (INFMT == 0) {                                                              \
            uint_t u = *reinterpret_cast<const uint_t*>(                               \
                (const s8_t*)featv + (size_t)sM * 64 + q * 4);                         \
            a0 += pM * (float)(s8_t)(u & 0xFF);                                        \
            a1 += pM * (float)(s8_t)((u >> 8) & 0xFF);                                 \
            a2 += pM * (float)(s8_t)((u >> 16) & 0xFF);                                \
            a3 += pM * (float)(s8_t)(u >> 24);                                         \
        } else {                                                                       \
            uint2 u = *reinterpret_cast<const uint2*>(                                 \
                (const ushort_t*)featv + (size_t)sM * 64 + q * 4);                     \
            a0 += pM * bf_lo(u.x); a1 += pM * bf_hi(u.x);                              \
            a2 += pM * bf_lo(u.y); a3 += pM * bf_hi(u.y);                              \
        }                                                                              \
    }

    int head = (deg < 32) ? deg : 32;
    int i = 0;
    for (; i + 2 <= head; i += 2) {
        float pA = __shfl(ps0, i, 32), pB = __shfl(ps0, i + 1, 32);
        int sA = __shfl(s0, i, 32), sB = __shfl(s0, i + 1, 32);
        GATHER_PAIR(sA, pA, sB, pB);
    }
    if (i < head) {  // odd tail within head
        float pA = __shfl(ps0, i, 32);
        int sA = __shfl(s0, i, 32);
        GATHER_PAIR(sA, pA, sA, 0.f);
    }
    for (i = 32; i < deg; i += 2) {  // rare tail (deg>32), paired with recomputed p
        int sA = csrsrc[start + i];
        int sB = sA; float pA, pB = 0.f;
        if (INFMT == 0) {
            float2 es = elscl[sA];
            pA = __expf(leaky(es.x + ern) - m) * es.y;
            if (i + 1 < deg) {
                sB = csrsrc[start + i + 1];
                float2 es2 = elscl[sB];
                pB = __expf(leaky(es2.x + ern) - m) * es2.y;
            }
        } else {
            pA = __expf(leaky(elp[sA] + ern) - m);
            if (i + 1 < deg) {
                sB = csrsrc[start + i + 1];
                pB = __expf(leaky(elp[sB] + ern) - m);
            }
        }
        GATHER_PAIR(sA, pA, sB, pB);
    }
    #undef GATHER_PAIR

    // fold even/odd halves (lanes k and k+16 hold same cols)
    a0 += __shfl_xor(a0, 16); a1 += __shfl_xor(a1, 16);
    a2 += __shfl_xor(a2, 16); a3 += __shfl_xor(a3, 16);
    return make_float4(a0 * inv, a1 * inv, a2 * inv, a3 * inv);
}

// ---------------- L1 agg: int8 in, (+b1, relu), int8 out, writes packed elsclB + erB ----
__global__ void agg1_k(const int* __restrict__ off, const int* __restrict__ csrsrc,
                       const float2* __restrict__ elsclA, const float* __restrict__ erA,
                       const s8_t* __restrict__ feat8, const float* __restrict__ bias,
                       s8_t* __restrict__ hA8, const float* __restrict__ val2,
                       const float* __restrict__ var2, float2* __restrict__ elsclB,
                       float* __restrict__ erB, int N) {
    int g = blockIdx.x * blockDim.x + threadIdx.x;
    int node = g >> 5;
    int sub = threadIdx.x & 31;
    if (node >= N) return;
    float4 v = agg_node<0>(off, csrsrc, elsclA, nullptr, erA, feat8, node, sub);
    int q = sub & 15;
    float4 b4 = ((const float4*)bias)[q];
    float v0 = fmaxf(v.x + b4.x, 0.f), v1 = fmaxf(v.y + b4.y, 0.f);
    float v2 = fmaxf(v.z + b4.z, 0.f), v3 = fmaxf(v.w + b4.w, 0.f);

    float rm = fmaxf(fmaxf(v0, v1), fmaxf(v2, v3));  // >=0 after relu
    for (int o = 8; o; o >>= 1) rm = fmaxf(rm, __shfl_xor(rm, o));
    float qi = (rm > 0.f) ? 127.f / rm : 0.f;
    int q0 = (int)rintf(v0 * qi), q1 = (int)rintf(v1 * qi);
    int q2 = (int)rintf(v2 * qi), q3 = (int)rintf(v3 * qi);
    if (sub < 16)
        ((uint_t*)hA8)[(size_t)node * 16 + q] =
            (uint_t)(q0 & 0xFF) | ((uint_t)(q1 & 0xFF) << 8) |
            ((uint_t)(q2 & 0xFF) << 16) | ((uint_t)(q3 & 0xFF) << 24);

    float4 wa = ((const float4*)val2)[q];
    float4 wb = ((const float4*)var2)[q];
    float a = v0 * wa.x + v1 * wa.y + v2 * wa.z + v3 * wa.w;
    float b = v0 * wb.x + v1 * wb.y + v2 * wb.z + v3 * wb.w;
    for (int o = 8; o; o >>= 1) { a += __shfl_xor(a, o); b += __shfl_xor(b, o); }
    if (sub == 0) {
        elsclB[node] = make_float2(a, rm * (1.f / 127.f));
        erB[node] = b;
    }
}

// ---------------- merged: L2 agg (-> LDS g) + h3 = relu(g@W2+b2) + feat3 = h3@W3 --------
__global__ void agg2_l23(const int* __restrict__ off, const int* __restrict__ csrsrc,
                         const float2* __restrict__ elsclB, const float* __restrict__ erB,
                         const s8_t* __restrict__ hA8, const ushort_t* __restrict__ Wt2,
                         const float* __restrict__ b2, const ushort_t* __restrict__ Wt3,
                         const float* __restrict__ al3, const float* __restrict__ ar3,
                         ushort_t* __restrict__ feat3, float* __restrict__ el,
                         float* __restrict__ er, int N) {
    __shared__ ushort_t gsh[16 * 64];     // 2 KB, XOR-swizzled (uint-pair j at j^((row&7)<<2))
    __shared__ ushort_t h3s[16 * 128];    // 4 KB, XOR-swizzled
    __shared__ float els[4][16], ers[4][16];
    int tid = threadIdx.x;
    int base = blockIdx.x * 16;

    // phase A: aggregate 16 nodes into swizzled LDS
    #pragma unroll
    for (int r = 0; r < 2; ++r) {
        int row = r * 8 + (tid >> 5);
        int node = base + row;
        int sub = tid & 31;
        float4 v = agg_node<0>(off, csrsrc, elsclB, nullptr, erB, hA8, node, sub);
        if (sub < 16) {
            int q = sub;
            uint2 pr;
            pr.x = ((uint_t)f2bf(v.y) << 16) | f2bf(v.x);
            pr.y = ((uint_t)f2bf(v.w) << 16) | f2bf(v.z);
            ((uint2*)gsh)[row * 16 + (q ^ ((row & 7) << 1))] = pr;
        }
    }
    __syncthreads();

    int wv = tid >> 6, lane = tid & 63;
    int c = lane & 15, kq = lane >> 4;

    // phase B: gemm1 K=64 -> M=128; A row = c from gsh
    bf16x8 a1[2];
    a1[0] = *reinterpret_cast<const bf16x8*>(&gsh[c * 64 + 8 * (kq ^ (c & 7))]);
    a1[1] = *reinterpret_cast<const bf16x8*>(&gsh[c * 64 + 8 * ((4 + kq) ^ (c & 7))]);

    f32x4 acc2[2];
    #pragma unroll
    for (int t = 0; t < 2; ++t) acc2[t] = (f32x4){0.f, 0.f, 0.f, 0.f};
    #pragma unroll
    for (int t = 0; t < 2; ++t) {
        int ct = wv * 2 + t;
        const ushort_t* bptr = Wt2 + (size_t)(ct * 16 + c) * 64 + kq * 8;
        acc2[t] = __builtin_amdgcn_mfma_f32_16x16x32_bf16(
            a1[0], *reinterpret_cast<const bf16x8*>(bptr), acc2[t], 0, 0, 0);
        acc2[t] = __builtin_amdgcn_mfma_f32_16x16x32_bf16(
            a1[1], *reinterpret_cast<const bf16x8*>(bptr + 32), acc2[t], 0, 0, 0);
    }
    #pragma unroll
    for (int t = 0; t < 2; ++t) {
        int ct = wv * 2 + t;
        float bv = b2[ct * 16 + c];
        #pragma unroll
        for (int j = 0; j < 4; ++j) {
            int r = kq * 4 + j;
            float v = fmaxf(acc2[t][j] + bv, 0.f);
            h3s[r * 128 + ((ct * 16 + c) ^ ((r & 7) << 3))] = f2bf(v);
        }
    }
    __syncthreads();

    // phase C: gemm2 K=128 -> M=64; wave wv does col tile wv; A row = c from h3s
    bf16x8 a2[4];
    #pragma unroll
    for (int ki = 0; ki < 4; ++ki)
        a2[ki] = *reinterpret_cast<const bf16x8*>(
            &h3s[c * 128 + 8 * ((ki * 4 + kq) ^ (c & 7))]);

    f32x4 acc3 = (f32x4){0.f, 0.f, 0.f, 0.f};
    const ushort_t* bptr3 = Wt3 + (size_t)(wv * 16 + c) * 128 + kq * 8;
    #pragma unroll
    for (int ki = 0; ki < 4; ++ki) {
        bf16x8 b = *reinterpret_cast<const bf16x8*>(bptr3 + ki * 32);
        acc3 = __builtin_amdgcn_mfma_f32_16x16x32_bf16(a2[ki], b, acc3, 0, 0, 0);
    }

    // epilogue: feat3 store + el3/er3 (cross-wave reduce)
    float alv = al3[wv * 16 + c], arv = ar3[wv * 16 + c];
    float pe[4], pr[4];
    #pragma unroll
    for (int j = 0; j < 4; ++j) {
        float v = acc3[j];
        feat3[(size_t)(base + kq * 4 + j) * 64 + wv * 16 + c] = f2bf(v);
        pe[j] = v * alv;
        pr[j] = v * arv;
    }
    #pragma unroll
    for (int o = 1; o < 16; o <<= 1) {
        #pragma unroll
        for (int j = 0; j < 4; ++j) {
            pe[j] += __shfl_xor(pe[j], o);
            pr[j] += __shfl_xor(pr[j], o);
        }
    }
    if (c == 0) {
        #pragma unroll
        for (int j = 0; j < 4; ++j) { els[wv][kq * 4 + j] = pe[j]; ers[wv][kq * 4 + j] = pr[j]; }
    }
    __syncthreads();
    if (tid < 16) {
        el[base + tid] = els[0][tid] + els[1][tid] + els[2][tid] + els[3][tid];
        er[base + tid] = ers[0][tid] + ers[1][tid] + ers[2][tid] + ers[3][tid];
    }
}

// ---------------- L3 agg: bf16 in, (+b3), fp32 out + link-pred partials ----------------
__global__ void agg3_k(const int* __restrict__ off, const int* __restrict__ csrsrc,
                       const float* __restrict__ elA, const float* __restrict__ erA,
                       const ushort_t* __restrict__ f3bf, const float* __restrict__ bias,
                       float* __restrict__ outh, const float* __restrict__ lpW,
                       float* __restrict__ s1, float* __restrict__ s2, int N) {
    int g = blockIdx.x * blockDim.x + threadIdx.x;
    int node = g >> 5;
    int sub = threadIdx.x & 31;
    if (node >= N) return;
    float4 v = agg_node<1>(off, csrsrc, nullptr, elA, erA, f3bf, node, sub);
    int q = sub & 15;
    float4 b4 = ((const float4*)bias)[q];
    float v0 = v.x + b4.x, v1 = v.y + b4.y, v2 = v.z + b4.z, v3 = v.w + b4.w;
    if (sub < 16)
        ((float4*)outh)[(size_t)node * 16 + q] = make_float4(v0, v1, v2, v3);

    float4 wa = ((const float4*)lpW)[q];
    float4 wb = ((const float4*)(lpW + 64))[q];
    float a = v0 * wa.x + v1 * wa.y + v2 * wa.z + v3 * wa.w;
    float b = v0 * wb.x + v1 * wb.y + v2 * wb.z + v3 * wb.w;
    for (int o = 8; o; o >>= 1) { a += __shfl_xor(a, o); b += __shfl_xor(b, o); }
    if (sub == 0) { s1[node] = a; s2[node] = b; }
}

// ---------------- MFMA GEMM core (K=128, M=64), A from fp32 X, int8 feat out + packed
// elscl, fused el/er epilogue ----------------
__device__ __forceinline__ void gemm64_f32core(const float* __restrict__ X,
                                               const ushort_t* __restrict__ Wt,
                                               const float* __restrict__ al,
                                               const float* __restrict__ ar,
                                               s8_t* __restrict__ feat8,
                                               float2* __restrict__ elscl,
                                               float* __restrict__ er,
                                               int N, int blk, int tid) {
    constexpr int CT = 4, KI = 4;
    int wv = tid >> 6, lane = tid & 63;
    int c = lane & 15, kq = lane >> 4;
    int n0 = blk * 64 + wv * 16;
    if (n0 >= N) return;

    const float* aptr = X + (size_t)(n0 + c) * 128 + kq * 8;
    bf16x8 a[KI];
    #pragma unroll
    for (int ki = 0; ki < KI; ++ki) {
        float4 f0 = *reinterpret_cast<const float4*>(aptr + ki * 32);
        float4 f1 = *reinterpret_cast<const float4*>(aptr + ki * 32 + 4);
        union { bf16x8 v; ushort_t u[8]; } pk;
        pk.u[0] = f2bf(f0.x); pk.u[1] = f2bf(f0.y); pk.u[2] = f2bf(f0.z); pk.u[3] = f2bf(f0.w);
        pk.u[4] = f2bf(f1.x); pk.u[5] = f2bf(f1.y); pk.u[6] = f2bf(f1.z); pk.u[7] = f2bf(f1.w);
        a[ki] = pk.v;
    }

    f32x4 acc[CT];
    #pragma unroll
    for (int ct = 0; ct < CT; ++ct) acc[ct] = (f32x4){0.f, 0.f, 0.f, 0.f};

    #pragma unroll
    for (int ct = 0; ct < CT; ++ct) {
        const ushort_t* bptr = Wt + (size_t)(ct * 16 + c) * 128 + kq * 8;
        #pragma unroll
        for (int ki = 0; ki < KI; ++ki) {
            bf16x8 b = *reinterpret_cast<const bf16x8*>(bptr + ki * 32);
            acc[ct] = __builtin_amdgcn_mfma_f32_16x16x32_bf16(a[ki], b, acc[ct], 0, 0, 0);
        }
    }

    float pe[4] = {0.f, 0.f, 0.f, 0.f}, pr[4] = {0.f, 0.f, 0.f, 0.f};
    float pm[4] = {0.f, 0.f, 0.f, 0.f};
    #pragma unroll
    for (int ct = 0; ct < CT; ++ct) {
        float alv = al[ct * 16 + c], arv = ar[ct * 16 + c];
        #pragma unroll
        for (int j = 0; j < 4; ++j) {
            float v = acc[ct][j];
            pe[j] += v * alv;
            pr[j] += v * arv;
            pm[j] = fmaxf(pm[j], fabsf(v));
        }
    }
    #pragma unroll
    for (int o = 1; o < 16; o <<= 1) {
        #pragma unroll
        for (int j = 0; j < 4; ++j) {
            pe[j] += __shfl_xor(pe[j], o);
            pr[j] += __shfl_xor(pr[j], o);
            pm[j] = fmaxf(pm[j], __shfl_xor(pm[j], o));
        }
    }
    #pragma unroll
    for (int j = 0; j < 4; ++j) {
        float qi = (pm[j] > 0.f) ? 127.f / pm[j] : 0.f;
        int row = n0 + kq * 4 + j;
        #pragma unroll
        for (int ct = 0; ct < CT; ++ct) {
            int q = (int)rintf(acc[ct][j] * qi);
            feat8[(size_t)row * 64 + ct * 16 + c] = (s8_t)q;
        }
    }
    if (c == 0) {
        #pragma unroll
        for (int j = 0; j < 4; ++j) {
            elscl[n0 + kq * 4 + j] = make_float2(pe[j], pm[j] * (1.f / 127.f));
            er[n0 + kq * 4 + j] = pr[j];
        }
    }
}

// ---------------- bucket_csr + L1 gemm fused ----------------
__global__ void csr_gemm1(const uint_t* __restrict__ pairbuf, const uint_t* __restrict__ bucketbase,
                          int* __restrict__ off, int* __restrict__ csrsrc,
                          const float* __restrict__ X, const ushort_t* __restrict__ Wt1,
                          const float* __restrict__ al1, const float* __restrict__ ar1,
                          s8_t* __restrict__ feat8, float2* __restrict__ elsclA,
                          float* __restrict__ erA, int N) {
    __shared__ uint_t cnt[256];
    __shared__ uint_t ws4[4];
    int tid = threadIdx.x;
    if (blockIdx.x >= NBKT) {  // gemm part
        gemm64_f32core(X, Wt1, al1, ar1, feat8, elsclA, erA, N, blockIdx.x - NBKT, tid);
        return;
    }
    // bucket_csr part
    int b = blockIdx.x;
    uint_t eb0 = bucketbase[b], m = bucketbase[b + 1] - eb0;
    cnt[tid] = 0;
    __syncthreads();
    for (uint_t i = tid; i < m; i += 256)
        atomicAdd(&cnt[pairbuf[eb0 + i] >> 16], 1u);
    __syncthreads();
    uint_t v = cnt[tid];
    int lane = tid & 63, w = tid >> 6;
    uint_t sc = v;
    for (int o = 1; o < 64; o <<= 1) {
        uint_t x = __shfl_up(sc, o);
        if (lane >= o) sc += x;
    }
    if (lane == 63) ws4[w] = sc;
    __syncthreads();
    if (tid == 0) { uint_t r = 0; for (int i = 0; i < 4; ++i) { uint_t tmp = ws4[i]; ws4[i] = r; r += tmp; } }
    __syncthreads();
    uint_t excl = ws4[w] + sc - v;
    int node = b * 256 + tid;
    if (node < NN) off[node] = (int)(eb0 + excl);
    if (b == 0 && tid == 0) off[NN] = NE;
    __syncthreads();
    cnt[tid] = eb0 + excl;  // reuse as cursor
    __syncthreads();
    for (uint_t i = tid; i < m; i += 256) {
        uint_t p = pairbuf[eb0 + i];
        uint_t pos = atomicAdd(&cnt[p >> 16], 1u);
        csrsrc[pos] = (int)(p & 0xFFFFu);
    }
}

// ---------------- scores: 4 edges per thread, both lists in one launch ----------------
__global__ void scores4_k(const int4* __restrict__ s4, const int4* __restrict__ d4,
                          const int4* __restrict__ ns4, const int4* __restrict__ nd4,
                          const float* __restrict__ s1, const float* __restrict__ s2,
                          const float* __restrict__ lpb,
                          float4* __restrict__ outp, float4* __restrict__ outn, int E4) {
    int i = blockIdx.x * blockDim.x + threadIdx.x;
    float cc = lpb[0];
    if (i < E4) {
        int4 s = s4[i], d = d4[i];
        outp[i] = make_float4(s1[s.x] + s2[d.x] + cc, s1[s.y] + s2[d.y] + cc,
                              s1[s.z] + s2[d.z] + cc, s1[s.w] + s2[d.w] + cc);
    } else if (i < 2 * E4) {
        int j = i - E4;
        int4 s = ns4[j], d = nd4[j];
        outn[j] = make_float4(s1[s.x] + s2[d.x] + cc, s1[s.y] + s2[d.y] + cc,
                              s1[s.z] + s2[d.z] + cc, s1[s.w] + s2[d.w] + cc);
    }
}

// ---------------- driver ----------------

struct Scratch {
    ushort_t* wt1; ushort_t* wt2; ushort_t* wt3;
    s8_t* feat8; s8_t* hA8;
    ushort_t* f3bf;
    float2* elsclA; float2* elsclB;
    float* erA; float* erB;
    float* elL3; float* erL3;
    float* val2; float* var2; float* s1; float* s2;
    int* off; int* csrsrc; uint_t* gh; uint_t* bucketbase;
    uint_t* pairbuf;
};

extern "C" void kernel_launch(void* const* d_in, const int* in_sizes, int n_in,
                              void* d_out, int out_size, void* d_ws, size_t ws_size,
                              hipStream_t stream) {
    const float* x   = (const float*)d_in[0];
    const float* W1  = (const float*)d_in[1];
    const float* al1 = (const float*)d_in[2];
    const float* ar1 = (const float*)d_in[3];
    const float* b1  = (const float*)d_in[4];
    const float* W2  = (const float*)d_in[5];
    const float* al2 = (const float*)d_in[6];
    const float* ar2 = (const float*)d_in[7];
    const float* b2  = (const float*)d_in[8];
    const float* W3  = (const float*)d_in[9];
    const float* al3 = (const float*)d_in[10];
    const float* ar3 = (const float*)d_in[11];
    const float* b3  = (const float*)d_in[12];
    const float* lpW = (const float*)d_in[13];
    const float* lpb = (const float*)d_in[14];
    const int* src  = (const int*)d_in[15];
    const int* dst  = (const int*)d_in[16];
    const int* nsrc = (const int*)d_in[17];
    const int* ndst = (const int*)d_in[18];

    char* w = (char*)d_ws;
    Scratch S;
    S.feat8      = (s8_t*)w;     w += (size_t)NN * 64;
    S.hA8        = (s8_t*)w;     w += (size_t)NN * 64;
    S.f3bf       = (ushort_t*)w; w += (size_t)NN * 64 * 2;
    S.elsclA     = (float2*)w;   w += (size_t)NN * 8;
    S.elsclB     = (float2*)w;   w += (size_t)NN * 8;
    S.erA        = (float*)w;    w += (size_t)NN * 4;
    S.erB        = (float*)w;    w += (size_t)NN * 4;
    S.elL3       = (float*)w;    w += (size_t)NN * 4;
    S.erL3       = (float*)w;    w += (size_t)NN * 4;
    S.wt1        = (ushort_t*)w; w += 128 * 64 * 2;
    S.wt2        = (ushort_t*)w; w += 64 * 128 * 2;
    S.wt3        = (ushort_t*)w; w += 128 * 64 * 2;
    S.val2       = (float*)w;    w += 64 * 4;
    S.var2       = (float*)w;    w += 64 * 4;
    S.s1         = (float*)w;    w += (size_t)NN * 4;
    S.s2         = (float*)w;    w += (size_t)NN * 4;
    S.off        = (int*)w;      w += (size_t)(NN + 1) * 4;
    S.csrsrc     = (int*)w;      w += (size_t)NE * 4;
    S.gh         = (uint_t*)w;   w += (size_t)NBKT * NT * 4;
    S.bucketbase = (uint_t*)w;   w += (size_t)(NBKT + 1) * 4;
    S.pairbuf    = (uint_t*)w;   w += (size_t)NE * 4;

    const int GEMM_GRID = (NN + 63) / 64;      // 782
    const int AGG_GRID = (NN * 32 + 255) / 256;

    // 1) histogram + weight prep
    prep_hist<<<NT + WBLK + 1, 256, 0, stream>>>(
        W1, W2, W3, S.wt1, S.wt2, S.wt3, al2, ar2, S.val2, S.var2, dst, S.gh);
    // 2) scan
    scan_gh<<<1, 1024, 0, stream>>>(S.gh, S.bucketbase);
    // 3) bucket-scatter pairs
    part_scatter<<<NT, 256, 0, stream>>>(src, dst, S.gh, S.bucketbase, S.pairbuf);
    // 4) CSR finalize + L1 gemm (int8 feat + packed elsclA)
    csr_gemm1<<<NBKT + GEMM_GRID, 256, 0, stream>>>(
        S.pairbuf, S.bucketbase, S.off, S.csrsrc,
        x, S.wt1, al1, ar1, S.feat8, S.elsclA, S.erA, NN);

    float* out_h   = (float*)d_out;
    float* out_pos = out_h + (size_t)NN * 64;
    float* out_neg = out_pos + NE;

    // 5) L1 agg -> hA8 + packed elsclB/erB
    agg1_k<<<AGG_GRID, 256, 0, stream>>>(
        S.off, S.csrsrc, S.elsclA, S.erA, S.feat8, b1, S.hA8,
        S.val2, S.var2, S.elsclB, S.erB, NN);
    // 6) merged L2 agg + both GEMMs -> feat3 + el3/er3
    agg2_l23<<<NN / 16, 256, 0, stream>>>(
        S.off, S.csrsrc, S.elsclB, S.erB, S.hA8, S.wt2, b2, S.wt3, al3, ar3,
        S.f3bf, S.elL3, S.erL3, NN);
    // 7) L3 agg -> d_out h + s1/s2
    agg3_k<<<AGG_GRID, 256, 0, stream>>>(
        S.off, S.csrsrc, S.elL3, S.erL3, S.f3bf, b3, out_h, lpW, S.s1, S.s2, NN);
    // 8) scores
    const int E4 = NE / 4;
    scores4_k<<<(2 * E4 + 255) / 256, 256, 0, stream>>>(
        (const int4*)src, (const int4*)dst, (const int4*)nsrc, (const int4*)ndst,
        S.s1, S.s2, lpb, (float4*)out_pos, (float4*)out_neg, E4);
}

// Round 18
// 148.638 us; speedup vs baseline: 1.0935x; 1.0935x over previous
//
#include <hip/hip_runtime.h>
#include <hip/hip_bf16.h>

#define NN 50000
#define NE 800000
#define NBKT 196        // ceil(NN/256) buckets of 256 nodes
#define NT 200          // partition tiles
#define TILE 4000       // NE/NT exactly

typedef unsigned short ushort_t;
typedef unsigned int uint_t;
typedef signed char s8_t;

typedef __bf16 bf16_t;
typedef bf16_t bf16x8 __attribute__((ext_vector_type(8)));
typedef float f32x4 __attribute__((ext_vector_type(4)));

__device__ __forceinline__ float leaky(float v) { return (v >= 0.f) ? v : 0.2f * v; }
__device__ __forceinline__ ushort_t f2bf(float f) {
    __hip_bfloat16 h = __float2bfloat16(f);
    return *reinterpret_cast<ushort_t*>(&h);
}
__device__ __forceinline__ float bf_lo(uint_t v) { return __uint_as_float(v << 16); }
__device__ __forceinline__ float bf_hi(uint_t v) { return __uint_as_float(v & 0xFFFF0000u); }

// ---------------- prep + hist ----------------

#define WELEM (128 * 64 * 3)
#define WBLK 96

__global__ void prep_hist(const float* __restrict__ W1, const float* __restrict__ W2,
                          const float* __restrict__ W3, ushort_t* __restrict__ Wt1,
                          ushort_t* __restrict__ Wt2, ushort_t* __restrict__ Wt3,
                          const float* __restrict__ al2, const float* __restrict__ ar2,
                          float* __restrict__ val2, float* __restrict__ var2,
                          const int* __restrict__ dst, uint_t* __restrict__ gh) {
    __shared__ uint_t h[NBKT];
    int tid = threadIdx.x;
    int blk = blockIdx.x;
    if (blk < NT) {  // histogram tile
        for (int i = tid; i < NBKT; i += 256) h[i] = 0;
        __syncthreads();
        int e0 = blk * TILE;
        for (int i = tid; i < TILE; i += 256)
            atomicAdd(&h[((uint_t)dst[e0 + i]) >> 8], 1u);
        __syncthreads();
        for (int i = tid; i < NBKT; i += 256) gh[(size_t)i * NT + blk] = h[i];
        return;
    }
    blk -= NT;
    if (blk < WBLK) {  // weights -> bf16^T, 1 elem/thread
        int gw = blk * 256 + tid;
        if (gw < 128 * 64) {
            int i = gw; int k = i >> 6, m = i & 63;
            Wt1[m * 128 + k] = f2bf(W1[i]);
        } else if (gw < 2 * 128 * 64) {
            int i = gw - 128 * 64; int k = i >> 7, m = i & 127;
            Wt2[m * 64 + k] = f2bf(W2[i]);
        } else if (gw < WELEM) {
            int i = gw - 2 * 128 * 64; int k = i >> 6, m = i & 63;
            Wt3[m * 128 + k] = f2bf(W3[i]);
        }
        return;
    }
    // last block: layer-2 attention vectors
    if (tid < 128) {
        int k = tid & 63;
        const float* av = (tid < 64) ? al2 : ar2;
        float acc = 0.f;
        const float* row = W2 + k * 128;
        #pragma unroll 8
        for (int m = 0; m < 128; ++m) acc += row[m] * av[m];
        if (tid < 64) val2[k] = acc; else var2[k] = acc;
    }
}

// ---------------- scan: wave-per-bucket over tiles ----------------
__global__ void scan_gh(uint_t* __restrict__ gh, uint_t* __restrict__ bucketbase) {
    __shared__ uint_t btot[NBKT];
    __shared__ uint_t ws4[4];
    int tid = threadIdx.x;          // 1024 threads, 16 waves
    int wv = tid >> 6, lane = tid & 63;
    for (int b = wv; b < NBKT; b += 16) {
        uint_t* row = gh + (size_t)b * NT;
        uint_t carry = 0;
        for (int base = 0; base < NT; base += 64) {
            int idx = base + lane;
            uint_t v = (idx < NT) ? row[idx] : 0;
            uint_t sc = v;
            for (int o = 1; o < 64; o <<= 1) {
                uint_t xx = __shfl_up(sc, o);
                if (lane >= o) sc += xx;
            }
            if (idx < NT) row[idx] = carry + sc - v;
            carry += __shfl(sc, 63);
        }
        if (lane == 0) btot[b] = carry;
    }
    __syncthreads();
    uint_t v = 0, sc = 0;
    if (tid < 256) {
        v = (tid < NBKT) ? btot[tid] : 0;
        sc = v;
        for (int o = 1; o < 64; o <<= 1) {
            uint_t xx = __shfl_up(sc, o);
            if ((tid & 63) >= o) sc += xx;
        }
        if ((tid & 63) == 63) ws4[tid >> 6] = sc;
    }
    __syncthreads();
    if (tid == 0) {
        uint_t r = 0;
        for (int i = 0; i < 4; ++i) { uint_t tmp = ws4[i]; ws4[i] = r; r += tmp; }
    }
    __syncthreads();
    if (tid < NBKT) bucketbase[tid] = ws4[tid >> 6] + sc - v;
    if (tid == 0) bucketbase[NBKT] = NE;
}

__global__ void part_scatter(const int* __restrict__ src, const int* __restrict__ dst,
                             const uint_t* __restrict__ gh, const uint_t* __restrict__ bucketbase,
                             uint_t* __restrict__ pairbuf) {
    __shared__ uint_t cur[NBKT];
    int t = blockIdx.x, tid = threadIdx.x;
    for (int i = tid; i < NBKT; i += 256)
        cur[i] = gh[(size_t)i * NT + t] + bucketbase[i];
    __syncthreads();
    int e0 = t * TILE;
    for (int i = tid; i < TILE; i += 256) {
        int d = dst[e0 + i], s = src[e0 + i];
        uint_t pos = atomicAdd(&cur[((uint_t)d) >> 8], 1u);
        pairbuf[pos] = (uint_t)s | (((uint_t)d & 255u) << 16);
    }
}

// ---------------- shared agg core (round-16 shape, 8-deep MLP unroll) ------------------
// INFMT 0: int8 feat + packed float2 {el,scl}; INFMT 1: bf16 feat + plain el.
template <int INFMT>
__device__ __forceinline__ float2 agg_node(const int* __restrict__ off,
                                           const int* __restrict__ csrsrc,
                                           const float2* __restrict__ elscl,
                                           const float* __restrict__ elp,
                                           const float* __restrict__ er,
                                           const void* __restrict__ featv,
                                           int node, int sub) {
    int start = off[node], deg = off[node + 1] - start;
    float ern = er[node];

    int s0 = 0; float e0 = -1e30f; float sc0 = 0.f;
    if (sub < deg) {
        s0 = csrsrc[start + sub];
        if (INFMT == 0) { float2 es = elscl[s0]; e0 = leaky(es.x + ern); sc0 = es.y; }
        else            { e0 = leaky(elp[s0] + ern); }
    }
    float m = e0;
    for (int i = 32 + sub; i < deg; i += 32) {
        int s = csrsrc[start + i];
        float ev = (INFMT == 0) ? elscl[s].x : elp[s];
        m = fmaxf(m, leaky(ev + ern));
    }
    for (int o = 16; o; o >>= 1) m = fmaxf(m, __shfl_xor(m, o));

    float p0 = (sub < deg) ? __expf(e0 - m) : 0.f;
    float ssum = p0;
    for (int i = 32 + sub; i < deg; i += 32) {
        int s = csrsrc[start + i];
        float ev = (INFMT == 0) ? elscl[s].x : elp[s];
        ssum += __expf(leaky(ev + ern) - m);
    }
    for (int o = 16; o; o >>= 1) ssum += __shfl_xor(ssum, o);
    float inv = (deg > 0) ? 1.f / ssum : 0.f;

    float ps0 = (INFMT == 0) ? p0 * sc0 : p0;

    float acc0 = 0.f, acc1 = 0.f;
    int head = (deg < 32) ? deg : 32;
    int i = 0;
    // 8-deep unroll: 8 independent gathers in flight
    for (; i + 8 <= head; i += 8) {
        float p[8]; int s[8];
        #pragma unroll
        for (int k = 0; k < 8; ++k) {
            p[k] = __shfl(ps0, i + k, 32);
            s[k] = __shfl(s0, i + k, 32);
        }
        if (INFMT == 0) {
            const s8_t* base = (const s8_t*)featv;
            ushort_t u[8];
            #pragma unroll
            for (int k = 0; k < 8; ++k)
                u[k] = ((const ushort_t*)(base + (size_t)s[k] * 64))[sub];
            #pragma unroll
            for (int k = 0; k < 8; ++k) {
                acc0 += p[k] * (float)(s8_t)(u[k] & 0xFF);
                acc1 += p[k] * (float)(s8_t)(u[k] >> 8);
            }
        } else {
            const ushort_t* base = (const ushort_t*)featv;
            uint_t u[8];
            #pragma unroll
            for (int k = 0; k < 8; ++k)
                u[k] = ((const uint_t*)(base + (size_t)s[k] * 64))[sub];
            #pragma unroll
            for (int k = 0; k < 8; ++k) {
                acc0 += p[k] * bf_lo(u[k]);
                acc1 += p[k] * bf_hi(u[k]);
            }
        }
    }
    for (; i + 4 <= head; i += 4) {
        float pA = __shfl(ps0, i, 32), pB = __shfl(ps0, i + 1, 32),
              pC = __shfl(ps0, i + 2, 32), pD = __shfl(ps0, i + 3, 32);
        int sA = __shfl(s0, i, 32), sB = __shfl(s0, i + 1, 32),
            sC = __shfl(s0, i + 2, 32), sD = __shfl(s0, i + 3, 32);
        if (INFMT == 0) {
            const s8_t* base = (const s8_t*)featv;
            ushort_t uA = ((const ushort_t*)(base + (size_t)sA * 64))[sub];
            ushort_t uB = ((const ushort_t*)(base + (size_t)sB * 64))[sub];
            ushort_t uC = ((const ushort_t*)(base + (size_t)sC * 64))[sub];
            ushort_t uD = ((const ushort_t*)(base + (size_t)sD * 64))[sub];
            acc0 += pA * (float)(s8_t)(uA & 0xFF) + pB * (float)(s8_t)(uB & 0xFF)
                  + pC * (float)(s8_t)(uC & 0xFF) + pD * (float)(s8_t)(uD & 0xFF);
            acc1 += pA * (float)(s8_t)(uA >> 8) + pB * (float)(s8_t)(uB >> 8)
                  + pC * (float)(s8_t)(uC >> 8) + pD * (float)(s8_t)(uD >> 8);
        } else {
            const ushort_t* base = (const ushort_t*)featv;
            uint_t vA = ((const uint_t*)(base + (size_t)sA * 64))[sub];
            uint_t vB = ((const uint_t*)(base + (size_t)sB * 64))[sub];
            uint_t vC = ((const uint_t*)(base + (size_t)sC * 64))[sub];
            uint_t vD = ((const uint_t*)(base + (size_t)sD * 64))[sub];
            acc0 += pA * bf_lo(vA) + pB * bf_lo(vB) + pC * bf_lo(vC) + pD * bf_lo(vD);
            acc1 += pA * bf_hi(vA) + pB * bf_hi(vB) + pC * bf_hi(vC) + pD * bf_hi(vD);
        }
    }
    for (; i < head; ++i) {
        float p = __shfl(ps0, i, 32);
        int sN = __shfl(s0, i, 32);
        if (INFMT == 0) {
            ushort_t u = ((const ushort_t*)((const s8_t*)featv + (size_t)sN * 64))[sub];
            acc0 += p * (float)(s8_t)(u & 0xFF);
            acc1 += p * (float)(s8_t)(u >> 8);
        } else {
            uint_t v = ((const uint_t*)((const ushort_t*)featv + (size_t)sN * 64))[sub];
            acc0 += p * bf_lo(v); acc1 += p * bf_hi(v);
        }
    }
    for (i = 32; i < deg; ++i) {  // rare tail (deg>32)
        int sN = csrsrc[start + i];
        float p;
        if (INFMT == 0) {
            float2 es = elscl[sN];
            p = __expf(leaky(es.x + ern) - m) * es.y;
            ushort_t u = ((const ushort_t*)((const s8_t*)featv + (size_t)sN * 64))[sub];
            acc0 += p * (float)(s8_t)(u & 0xFF);
            acc1 += p * (float)(s8_t)(u >> 8);
        } else {
            p = __expf(leaky(elp[sN] + ern) - m);
            uint_t v = ((const uint_t*)((const ushort_t*)featv + (size_t)sN * 64))[sub];
            acc0 += p * bf_lo(v); acc1 += p * bf_hi(v);
        }
    }
    return make_float2(acc0 * inv, acc1 * inv);
}

// ---------------- L1 agg: int8 in, (+b1, relu), int8 out, writes packed elsclB + erB ----
__global__ void agg1_k(const int* __restrict__ off, const int* __restrict__ csrsrc,
                       const float2* __restrict__ elsclA, const float* __restrict__ erA,
                       const s8_t* __restrict__ feat8, const float* __restrict__ bias,
                       s8_t* __restrict__ hA8, const float* __restrict__ val2,
                       const float* __restrict__ var2, float2* __restrict__ elsclB,
                       float* __restrict__ erB, int N) {
    int g = blockIdx.x * blockDim.x + threadIdx.x;
    int node = g >> 5;
    int sub = threadIdx.x & 31;
    if (node >= N) return;
    float2 v = agg_node<0>(off, csrsrc, elsclA, nullptr, erA, feat8, node, sub);
    float2 b2 = ((const float2*)bias)[sub];
    float v0 = fmaxf(v.x + b2.x, 0.f), v1 = fmaxf(v.y + b2.y, 0.f);

    float rm = fmaxf(v0, v1);  // values are >=0 after relu
    for (int o = 16; o; o >>= 1) rm = fmaxf(rm, __shfl_xor(rm, o));
    float qi = (rm > 0.f) ? 127.f / rm : 0.f;
    int q0 = (int)rintf(v0 * qi), q1 = (int)rintf(v1 * qi);
    ((ushort_t*)hA8)[(size_t)node * 32 + sub] =
        (ushort_t)((q0 & 0xFF) | ((q1 & 0xFF) << 8));

    float2 wa = ((const float2*)val2)[sub];
    float2 wb = ((const float2*)var2)[sub];
    float a = v0 * wa.x + v1 * wa.y;
    float b = v0 * wb.x + v1 * wb.y;
    for (int o = 16; o; o >>= 1) { a += __shfl_xor(a, o); b += __shfl_xor(b, o); }
    if (sub == 0) {
        elsclB[node] = make_float2(a, rm * (1.f / 127.f));
        erB[node] = b;
    }
}

// ---------------- merged: L2 agg (-> LDS g) + h3 = relu(g@W2+b2) + feat3 = h3@W3 --------
__global__ void agg2_l23(const int* __restrict__ off, const int* __restrict__ csrsrc,
                         const float2* __restrict__ elsclB, const float* __restrict__ erB,
                         const s8_t* __restrict__ hA8, const ushort_t* __restrict__ Wt2,
                         const float* __restrict__ b2, const ushort_t* __restrict__ Wt3,
                         const float* __restrict__ al3, const float* __restrict__ ar3,
                         ushort_t* __restrict__ feat3, float* __restrict__ el,
                         float* __restrict__ er, int N) {
    __shared__ ushort_t gsh[16 * 64];     // 2 KB, XOR-swizzled (8-col groups ^ row&7)
    __shared__ ushort_t h3s[16 * 128];    // 4 KB, XOR-swizzled
    __shared__ float els[4][16], ers[4][16];
    int tid = threadIdx.x;
    int base = blockIdx.x * 16;

    // phase A: aggregate 16 nodes into swizzled LDS
    #pragma unroll
    for (int r = 0; r < 2; ++r) {
        int row = r * 8 + (tid >> 5);
        int node = base + row;
        int sub = tid & 31;
        float2 v = agg_node<0>(off, csrsrc, elsclB, nullptr, erB, hA8, node, sub);
        int colu = sub ^ ((row & 7) << 2);   // uint-granularity swizzle
        ((uint_t*)gsh)[row * 32 + colu] = ((uint_t)f2bf(v.y) << 16) | f2bf(v.x);
    }
    __syncthreads();

    int wv = tid >> 6, lane = tid & 63;
    int c = lane & 15, kq = lane >> 4;

    // phase B: gemm1 K=64 -> M=128; A row = c from gsh
    bf16x8 a1[2];
    a1[0] = *reinterpret_cast<const bf16x8*>(&gsh[c * 64 + 8 * (kq ^ (c & 7))]);
    a1[1] = *reinterpret_cast<const bf16x8*>(&gsh[c * 64 + 8 * ((4 + kq) ^ (c & 7))]);

    f32x4 acc2[2];
    #pragma unroll
    for (int t = 0; t < 2; ++t) acc2[t] = (f32x4){0.f, 0.f, 0.f, 0.f};
    #pragma unroll
    for (int t = 0; t < 2; ++t) {
        int ct = wv * 2 + t;
        const ushort_t* bptr = Wt2 + (size_t)(ct * 16 + c) * 64 + kq * 8;
        acc2[t] = __builtin_amdgcn_mfma_f32_16x16x32_bf16(
            a1[0], *reinterpret_cast<const bf16x8*>(bptr), acc2[t], 0, 0, 0);
        acc2[t] = __builtin_amdgcn_mfma_f32_16x16x32_bf16(
            a1[1], *reinterpret_cast<const bf16x8*>(bptr + 32), acc2[t], 0, 0, 0);
    }
    #pragma unroll
    for (int t = 0; t < 2; ++t) {
        int ct = wv * 2 + t;
        float bv = b2[ct * 16 + c];
        #pragma unroll
        for (int j = 0; j < 4; ++j) {
            int r = kq * 4 + j;
            float v = fmaxf(acc2[t][j] + bv, 0.f);
            h3s[r * 128 + ((ct * 16 + c) ^ ((r & 7) << 3))] = f2bf(v);
        }
    }
    __syncthreads();

    // phase C: gemm2 K=128 -> M=64; wave wv does col tile wv; A row = c from h3s
    bf16x8 a2[4];
    #pragma unroll
    for (int ki = 0; ki < 4; ++ki)
        a2[ki] = *reinterpret_cast<const bf16x8*>(
            &h3s[c * 128 + 8 * ((ki * 4 + kq) ^ (c & 7))]);

    f32x4 acc3 = (f32x4){0.f, 0.f, 0.f, 0.f};
    const ushort_t* bptr3 = Wt3 + (size_t)(wv * 16 + c) * 128 + kq * 8;
    #pragma unroll
    for (int ki = 0; ki < 4; ++ki) {
        bf16x8 b = *reinterpret_cast<const bf16x8*>(bptr3 + ki * 32);
        acc3 = __builtin_amdgcn_mfma_f32_16x16x32_bf16(a2[ki], b, acc3, 0, 0, 0);
    }

    // epilogue: feat3 store + el3/er3 (cross-wave reduce)
    float alv = al3[wv * 16 + c], arv = ar3[wv * 16 + c];
    float pe[4], pr[4];
    #pragma unroll
    for (int j = 0; j < 4; ++j) {
        float v = acc3[j];
        feat3[(size_t)(base + kq * 4 + j) * 64 + wv * 16 + c] = f2bf(v);
        pe[j] = v * alv;
        pr[j] = v * arv;
    }
    #pragma unroll
    for (int o = 1; o < 16; o <<= 1) {
        #pragma unroll
        for (int j = 0; j < 4; ++j) {
            pe[j] += __shfl_xor(pe[j], o);
            pr[j] += __shfl_xor(pr[j], o);
        }
    }
    if (c == 0) {
        #pragma unroll
        for (int j = 0; j < 4; ++j) { els[wv][kq * 4 + j] = pe[j]; ers[wv][kq * 4 + j] = pr[j]; }
    }
    __syncthreads();
    if (tid < 16) {
        el[base + tid] = els[0][tid] + els[1][tid] + els[2][tid] + els[3][tid];
        er[base + tid] = ers[0][tid] + ers[1][tid] + ers[2][tid] + ers[3][tid];
    }
}

// ---------------- L3 agg: bf16 in, (+b3), fp32 out + link-pred partials ----------------
__global__ void agg3_k(const int* __restrict__ off, const int* __restrict__ csrsrc,
                       const float* __restrict__ elA, const float* __restrict__ erA,
                       const ushort_t* __restrict__ f3bf, const float* __restrict__ bias,
                       float* __restrict__ outh, const float* __restrict__ lpW,
                       float* __restrict__ s1, float* __restrict__ s2, int N) {
    int g = blockIdx.x * blockDim.x + threadIdx.x;
    int node = g >> 5;
    int sub = threadIdx.x & 31;
    if (node >= N) return;
    float2 v = agg_node<1>(off, csrsrc, nullptr, elA, erA, f3bf, node, sub);
    float2 b2 = ((const float2*)bias)[sub];
    float v0 = v.x + b2.x, v1 = v.y + b2.y;
    ((float2*)outh)[(size_t)node * 32 + sub] = make_float2(v0, v1);

    float2 wa = ((const float2*)lpW)[sub];
    float2 wb = ((const float2*)(lpW + 64))[sub];
    float a = v0 * wa.x + v1 * wa.y;
    float b = v0 * wb.x + v1 * wb.y;
    for (int o = 16; o; o >>= 1) { a += __shfl_xor(a, o); b += __shfl_xor(b, o); }
    if (sub == 0) { s1[node] = a; s2[node] = b; }
}

// ---------------- MFMA GEMM core (K=128, M=64), A from fp32 X, int8 feat out + packed
// elscl, fused el/er epilogue ----------------
__device__ __forceinline__ void gemm64_f32core(const float* __restrict__ X,
                                               const ushort_t* __restrict__ Wt,
                                               const float* __restrict__ al,
                                               const float* __restrict__ ar,
                                               s8_t* __restrict__ feat8,
                                               float2* __restrict__ elscl,
                                               float* __restrict__ er,
                                               int N, int blk, int tid) {
    constexpr int CT = 4, KI = 4;
    int wv = tid >> 6, lane = tid & 63;
    int c = lane & 15, kq = lane >> 4;
    int n0 = blk * 64 + wv * 16;
    if (n0 >= N) return;

    const float* aptr = X + (size_t)(n0 + c) * 128 + kq * 8;
    bf16x8 a[KI];
    #pragma unroll
    for (int ki = 0; ki < KI; ++ki) {
        float4 f0 = *reinterpret_cast<const float4*>(aptr + ki * 32);
        float4 f1 = *reinterpret_cast<const float4*>(aptr + ki * 32 + 4);
        union { bf16x8 v; ushort_t u[8]; } pk;
        pk.u[0] = f2bf(f0.x); pk.u[1] = f2bf(f0.y); pk.u[2] = f2bf(f0.z); pk.u[3] = f2bf(f0.w);
        pk.u[4] = f2bf(f1.x); pk.u[5] = f2bf(f1.y); pk.u[6] = f2bf(f1.z); pk.u[7] = f2bf(f1.w);
        a[ki] = pk.v;
    }

    f32x4 acc[CT];
    #pragma unroll
    for (int ct = 0; ct < CT; ++ct) acc[ct] = (f32x4){0.f, 0.f, 0.f, 0.f};

    #pragma unroll
    for (int ct = 0; ct < CT; ++ct) {
        const ushort_t* bptr = Wt + (size_t)(ct * 16 + c) * 128 + kq * 8;
        #pragma unroll
        for (int ki = 0; ki < KI; ++ki) {
            bf16x8 b = *reinterpret_cast<const bf16x8*>(bptr + ki * 32);
            acc[ct] = __builtin_amdgcn_mfma_f32_16x16x32_bf16(a[ki], b, acc[ct], 0, 0, 0);
        }
    }

    float pe[4] = {0.f, 0.f, 0.f, 0.f}, pr[4] = {0.f, 0.f, 0.f, 0.f};
    float pm[4] = {0.f, 0.f, 0.f, 0.f};
    #pragma unroll
    for (int ct = 0; ct < CT; ++ct) {
        float alv = al[ct * 16 + c], arv = ar[ct * 16 + c];
        #pragma unroll
        for (int j = 0; j < 4; ++j) {
            float v = acc[ct][j];
            pe[j] += v * alv;
            pr[j] += v * arv;
            pm[j] = fmaxf(pm[j], fabsf(v));
        }
    }
    #pragma unroll
    for (int o = 1; o < 16; o <<= 1) {
        #pragma unroll
        for (int j = 0; j < 4; ++j) {
            pe[j] += __shfl_xor(pe[j], o);
            pr[j] += __shfl_xor(pr[j], o);
            pm[j] = fmaxf(pm[j], __shfl_xor(pm[j], o));
        }
    }
    #pragma unroll
    for (int j = 0; j < 4; ++j) {
        float qi = (pm[j] > 0.f) ? 127.f / pm[j] : 0.f;
        int row = n0 + kq * 4 + j;
        #pragma unroll
        for (int ct = 0; ct < CT; ++ct) {
            int q = (int)rintf(acc[ct][j] * qi);
            feat8[(size_t)row * 64 + ct * 16 + c] = (s8_t)q;
        }
    }
    if (c == 0) {
        #pragma unroll
        for (int j = 0; j < 4; ++j) {
            elscl[n0 + kq * 4 + j] = make_float2(pe[j], pm[j] * (1.f / 127.f));
            er[n0 + kq * 4 + j] = pr[j];
        }
    }
}

// ---------------- bucket_csr + L1 gemm fused ----------------
__global__ void csr_gemm1(const uint_t* __restrict__ pairbuf, const uint_t* __restrict__ bucketbase,
                          int* __restrict__ off, int* __restrict__ csrsrc,
                          const float* __restrict__ X, const ushort_t* __restrict__ Wt1,
                          const float* __restrict__ al1, const float* __restrict__ ar1,
                          s8_t* __restrict__ feat8, float2* __restrict__ elsclA,
                          float* __restrict__ erA, int N) {
    __shared__ uint_t cnt[256];
    __shared__ uint_t ws4[4];
    int tid = threadIdx.x;
    if (blockIdx.x >= NBKT) {  // gemm part
        gemm64_f32core(X, Wt1, al1, ar1, feat8, elsclA, erA, N, blockIdx.x - NBKT, tid);
        return;
    }
    // bucket_csr part
    int b = blockIdx.x;
    uint_t eb0 = bucketbase[b], m = bucketbase[b + 1] - eb0;
    cnt[tid] = 0;
    __syncthreads();
    for (uint_t i = tid; i < m; i += 256)
        atomicAdd(&cnt[pairbuf[eb0 + i] >> 16], 1u);
    __syncthreads();
    uint_t v = cnt[tid];
    int lane = tid & 63, w = tid >> 6;
    uint_t sc = v;
    for (int o = 1; o < 64; o <<= 1) {
        uint_t x = __shfl_up(sc, o);
        if (lane >= o) sc += x;
    }
    if (lane == 63) ws4[w] = sc;
    __syncthreads();
    if (tid == 0) { uint_t r = 0; for (int i = 0; i < 4; ++i) { uint_t tmp = ws4[i]; ws4[i] = r; r += tmp; } }
    __syncthreads();
    uint_t excl = ws4[w] + sc - v;
    int node = b * 256 + tid;
    if (node < NN) off[node] = (int)(eb0 + excl);
    if (b == 0 && tid == 0) off[NN] = NE;
    __syncthreads();
    cnt[tid] = eb0 + excl;  // reuse as cursor
    __syncthreads();
    for (uint_t i = tid; i < m; i += 256) {
        uint_t p = pairbuf[eb0 + i];
        uint_t pos = atomicAdd(&cnt[p >> 16], 1u);
        csrsrc[pos] = (int)(p & 0xFFFFu);
    }
}

// ---------------- scores: 4 edges per thread, both lists in one launch ----------------
__global__ void scores4_k(const int4* __restrict__ s4, const int4* __restrict__ d4,
                          const int4* __restrict__ ns4, const int4* __restrict__ nd4,
                          const float* __restrict__ s1, const float* __restrict__ s2,
                          const float* __restrict__ lpb,
                          float4* __restrict__ outp, float4* __restrict__ outn, int E4) {
    int i = blockIdx.x * blockDim.x + threadIdx.x;
    float cc = lpb[0];
    if (i < E4) {
        int4 s = s4[i], d = d4[i];
        outp[i] = make_float4(s1[s.x] + s2[d.x] + cc, s1[s.y] + s2[d.y] + cc,
                              s1[s.z] + s2[d.z] + cc, s1[s.w] + s2[d.w] + cc);
    } else if (i < 2 * E4) {
        int j = i - E4;
        int4 s = ns4[j], d = nd4[j];
        outn[j] = make_float4(s1[s.x] + s2[d.x] + cc, s1[s.y] + s2[d.y] + cc,
                              s1[s.z] + s2[d.z] + cc, s1[s.w] + s2[d.w] + cc);
    }
}

// ---------------- driver ----------------

struct Scratch {
    ushort_t* wt1; ushort_t* wt2; ushort_t* wt3;
    s8_t* feat8; s8_t* hA8;
    ushort_t* f3bf;
    float2* elsclA; float2* elsclB;
    float* erA; float* erB;
    float* elL3; float* erL3;
    float* val2; float* var2; float* s1; float* s2;
    int* off; int* csrsrc; uint_t* gh; uint_t* bucketbase;
    uint_t* pairbuf;
};

extern "C" void kernel_launch(void* const* d_in, const int* in_sizes, int n_in,
                              void* d_out, int out_size, void* d_ws, size_t ws_size,
                              hipStream_t stream) {
    const float* x   = (const float*)d_in[0];
    const float* W1  = (const float*)d_in[1];
    const float* al1 = (const float*)d_in[2];
    const float* ar1 = (const float*)d_in[3];
    const float* b1  = (const float*)d_in[4];
    const float* W2  = (const float*)d_in[5];
    const float* al2 = (const float*)d_in[6];
    const float* ar2 = (const float*)d_in[7];
    const float* b2  = (const float*)d_in[8];
    const float* W3  = (const float*)d_in[9];
    const float* al3 = (const float*)d_in[10];
    const float* ar3 = (const float*)d_in[11];
    const float* b3  = (const float*)d_in[12];
    const float* lpW = (const float*)d_in[13];
    const float* lpb = (const float*)d_in[14];
    const int* src  = (const int*)d_in[15];
    const int* dst  = (const int*)d_in[16];
    const int* nsrc = (const int*)d_in[17];
    const int* ndst = (const int*)d_in[18];

    char* w = (char*)d_ws;
    Scratch S;
    S.feat8      = (s8_t*)w;     w += (size_t)NN * 64;
    S.hA8        = (s8_t*)w;     w += (size_t)NN * 64;
    S.f3bf       = (ushort_t*)w; w += (size_t)NN * 64 * 2;
    S.elsclA     = (float2*)w;   w += (size_t)NN * 8;
    S.elsclB     = (float2*)w;   w += (size_t)NN * 8;
    S.erA        = (float*)w;    w += (size_t)NN * 4;
    S.erB        = (float*)w;    w += (size_t)NN * 4;
    S.elL3       = (float*)w;    w += (size_t)NN * 4;
    S.erL3       = (float*)w;    w += (size_t)NN * 4;
    S.wt1        = (ushort_t*)w; w += 128 * 64 * 2;
    S.wt2        = (ushort_t*)w; w += 64 * 128 * 2;
    S.wt3        = (ushort_t*)w; w += 128 * 64 * 2;
    S.val2       = (float*)w;    w += 64 * 4;
    S.var2       = (float*)w;    w += 64 * 4;
    S.s1         = (float*)w;    w += (size_t)NN * 4;
    S.s2         = (float*)w;    w += (size_t)NN * 4;
    S.off        = (int*)w;      w += (size_t)(NN + 1) * 4;
    S.csrsrc     = (int*)w;      w += (size_t)NE * 4;
    S.gh         = (uint_t*)w;   w += (size_t)NBKT * NT * 4;
    S.bucketbase = (uint_t*)w;   w += (size_t)(NBKT + 1) * 4;
    S.pairbuf    = (uint_t*)w;   w += (size_t)NE * 4;

    const int GEMM_GRID = (NN + 63) / 64;      // 782
    const int AGG_GRID = (NN * 32 + 255) / 256;

    // 1) histogram + weight prep
    prep_hist<<<NT + WBLK + 1, 256, 0, stream>>>(
        W1, W2, W3, S.wt1, S.wt2, S.wt3, al2, ar2, S.val2, S.var2, dst, S.gh);
    // 2) scan
    scan_gh<<<1, 1024, 0, stream>>>(S.gh, S.bucketbase);
    // 3) bucket-scatter pairs
    part_scatter<<<NT, 256, 0, stream>>>(src, dst, S.gh, S.bucketbase, S.pairbuf);
    // 4) CSR finalize + L1 gemm (int8 feat + packed elsclA)
    csr_gemm1<<<NBKT + GEMM_GRID, 256, 0, stream>>>(
        S.pairbuf, S.bucketbase, S.off, S.csrsrc,
        x, S.wt1, al1, ar1, S.feat8, S.elsclA, S.erA, NN);

    float* out_h   = (float*)d_out;
    float* out_pos = out_h + (size_t)NN * 64;
    float* out_neg = out_pos + NE;

    // 5) L1 agg -> hA8 + packed elsclB/erB
    agg1_k<<<AGG_GRID, 256, 0, stream>>>(
        S.off, S.csrsrc, S.elsclA, S.erA, S.feat8, b1, S.hA8,
        S.val2, S.var2, S.elsclB, S.erB, NN);
    // 6) merged L2 agg + both GEMMs -> feat3 + el3/er3
    agg2_l23<<<NN / 16, 256, 0, stream>>>(
        S.off, S.csrsrc, S.elsclB, S.erB, S.hA8, S.wt2, b2, S.wt3, al3, ar3,
        S.f3bf, S.elL3, S.erL3, NN);
    // 7) L3 agg -> d_out h + s1/s2
    agg3_k<<<AGG_GRID, 256, 0, stream>>>(
        S.off, S.csrsrc, S.elL3, S.erL3, S.f3bf, b3, out_h, lpW, S.s1, S.s2, NN);
    // 8) scores
    const int E4 = NE / 4;
    scores4_k<<<(2 * E4 + 255) / 256, 256, 0, stream>>>(
        (const int4*)src, (const int4*)dst, (const int4*)nsrc, (const int4*)ndst,
        S.s1, S.s2, lpb, (float4*)out_pos, (float4*)out_neg, E4);
}

// Round 20
// 148.178 us; speedup vs baseline: 1.0969x; 1.0031x over previous
//
#include <hip/hip_runtime.h>
#include <hip/hip_bf16.h>

#define NN 50000
#define NE 800000
#define NBKT 196        // ceil(NN/256) buckets of 256 nodes
#define NT 200          // partition tiles
#define TILE 4000       // NE/NT exactly

typedef unsigned short ushort_t;
typedef unsigned int uint_t;
typedef signed char s8_t;

typedef __bf16 bf16_t;
typedef bf16_t bf16x8 __attribute__((ext_vector_type(8)));
typedef float f32x4 __attribute__((ext_vector_type(4)));

__device__ __forceinline__ float leaky(float v) { return (v >= 0.f) ? v : 0.2f * v; }
__device__ __forceinline__ ushort_t f2bf(float f) {
    __hip_bfloat16 h = __float2bfloat16(f);
    return *reinterpret_cast<ushort_t*>(&h);
}
__device__ __forceinline__ float bf_lo(uint_t v) { return __uint_as_float(v << 16); }
__device__ __forceinline__ float bf_hi(uint_t v) { return __uint_as_float(v & 0xFFFF0000u); }

// ---------------- prep + hist ----------------

#define WELEM (128 * 64 * 3)
#define WBLK 96

__global__ void prep_hist(const float* __restrict__ W1, const float* __restrict__ W2,
                          const float* __restrict__ W3, ushort_t* __restrict__ Wt1,
                          ushort_t* __restrict__ Wt2, ushort_t* __restrict__ Wt3,
                          const float* __restrict__ al2, const float* __restrict__ ar2,
                          float* __restrict__ val2, float* __restrict__ var2,
                          const int* __restrict__ dst, uint_t* __restrict__ gh) {
    __shared__ uint_t h[NBKT];
    int tid = threadIdx.x;
    int blk = blockIdx.x;
    if (blk < NT) {  // histogram tile
        for (int i = tid; i < NBKT; i += 256) h[i] = 0;
        __syncthreads();
        int e0 = blk * TILE;
        for (int i = tid; i < TILE; i += 256)
            atomicAdd(&h[((uint_t)dst[e0 + i]) >> 8], 1u);
        __syncthreads();
        for (int i = tid; i < NBKT; i += 256) gh[(size_t)i * NT + blk] = h[i];
        return;
    }
    blk -= NT;
    if (blk < WBLK) {  // weights -> bf16^T, 1 elem/thread
        int gw = blk * 256 + tid;
        if (gw < 128 * 64) {
            int i = gw; int k = i >> 6, m = i & 63;
            Wt1[m * 128 + k] = f2bf(W1[i]);
        } else if (gw < 2 * 128 * 64) {
            int i = gw - 128 * 64; int k = i >> 7, m = i & 127;
            Wt2[m * 64 + k] = f2bf(W2[i]);
        } else if (gw < WELEM) {
            int i = gw - 2 * 128 * 64; int k = i >> 6, m = i & 63;
            Wt3[m * 128 + k] = f2bf(W3[i]);
        }
        return;
    }
    // last block: layer-2 attention vectors
    if (tid < 128) {
        int k = tid & 63;
        const float* av = (tid < 64) ? al2 : ar2;
        float acc = 0.f;
        const float* row = W2 + k * 128;
        #pragma unroll 8
        for (int m = 0; m < 128; ++m) acc += row[m] * av[m];
        if (tid < 64) val2[k] = acc; else var2[k] = acc;
    }
}

// ---------------- scan: wave-per-bucket over tiles ----------------
__global__ void scan_gh(uint_t* __restrict__ gh, uint_t* __restrict__ bucketbase) {
    __shared__ uint_t btot[NBKT];
    __shared__ uint_t ws4[4];
    int tid = threadIdx.x;          // 1024 threads, 16 waves
    int wv = tid >> 6, lane = tid & 63;
    for (int b = wv; b < NBKT; b += 16) {
        uint_t* row = gh + (size_t)b * NT;
        uint_t carry = 0;
        for (int base = 0; base < NT; base += 64) {
            int idx = base + lane;
            uint_t v = (idx < NT) ? row[idx] : 0;
            uint_t sc = v;
            for (int o = 1; o < 64; o <<= 1) {
                uint_t xx = __shfl_up(sc, o);
                if (lane >= o) sc += xx;
            }
            if (idx < NT) row[idx] = carry + sc - v;
            carry += __shfl(sc, 63);
        }
        if (lane == 0) btot[b] = carry;
    }
    __syncthreads();
    uint_t v = 0, sc = 0;
    if (tid < 256) {
        v = (tid < NBKT) ? btot[tid] : 0;
        sc = v;
        for (int o = 1; o < 64; o <<= 1) {
            uint_t xx = __shfl_up(sc, o);
            if ((tid & 63) >= o) sc += xx;
        }
        if ((tid & 63) == 63) ws4[tid >> 6] = sc;
    }
    __syncthreads();
    if (tid == 0) {
        uint_t r = 0;
        for (int i = 0; i < 4; ++i) { uint_t tmp = ws4[i]; ws4[i] = r; r += tmp; }
    }
    __syncthreads();
    if (tid < NBKT) bucketbase[tid] = ws4[tid >> 6] + sc - v;
    if (tid == 0) bucketbase[NBKT] = NE;
}

__global__ void part_scatter(const int* __restrict__ src, const int* __restrict__ dst,
                             const uint_t* __restrict__ gh, const uint_t* __restrict__ bucketbase,
                             uint_t* __restrict__ pairbuf) {
    __shared__ uint_t cur[NBKT];
    int t = blockIdx.x, tid = threadIdx.x;
    for (int i = tid; i < NBKT; i += 256)
        cur[i] = gh[(size_t)i * NT + t] + bucketbase[i];
    __syncthreads();
    int e0 = t * TILE;
    for (int i = tid; i < TILE; i += 256) {
        int d = dst[e0 + i], s = src[e0 + i];
        uint_t pos = atomicAdd(&cur[((uint_t)d) >> 8], 1u);
        pairbuf[pos] = (uint_t)s | (((uint_t)d & 255u) << 16);
    }
}

// ---------------- shared agg core (8-deep MLP unroll) ------------------
// INFMT 0: int8 feat + packed float2 {el,scl}; INFMT 1: bf16 feat + plain el.
template <int INFMT>
__device__ __forceinline__ float2 agg_node(const int* __restrict__ off,
                                           const int* __restrict__ csrsrc,
                                           const float2* __restrict__ elscl,
                                           const float* __restrict__ elp,
                                           const float* __restrict__ er,
                                           const void* __restrict__ featv,
                                           int node, int sub) {
    int start = off[node], deg = off[node + 1] - start;
    float ern = er[node];

    int s0 = 0; float e0 = -1e30f; float sc0 = 0.f;
    if (sub < deg) {
        s0 = csrsrc[start + sub];
        if (INFMT == 0) { float2 es = elscl[s0]; e0 = leaky(es.x + ern); sc0 = es.y; }
        else            { e0 = leaky(elp[s0] + ern); }
    }
    float m = e0;
    for (int i = 32 + sub; i < deg; i += 32) {
        int s = csrsrc[start + i];
        float ev = (INFMT == 0) ? elscl[s].x : elp[s];
        m = fmaxf(m, leaky(ev + ern));
    }
    for (int o = 16; o; o >>= 1) m = fmaxf(m, __shfl_xor(m, o));

    float p0 = (sub < deg) ? __expf(e0 - m) : 0.f;
    float ssum = p0;
    for (int i = 32 + sub; i < deg; i += 32) {
        int s = csrsrc[start + i];
        float ev = (INFMT == 0) ? elscl[s].x : elp[s];
        ssum += __expf(leaky(ev + ern) - m);
    }
    for (int o = 16; o; o >>= 1) ssum += __shfl_xor(ssum, o);
    float inv = (deg > 0) ? 1.f / ssum : 0.f;

    float ps0 = (INFMT == 0) ? p0 * sc0 : p0;

    float acc0 = 0.f, acc1 = 0.f;
    int head = (deg < 32) ? deg : 32;
    int i = 0;
    // 8-deep unroll: 8 independent gathers in flight
    for (; i + 8 <= head; i += 8) {
        float p[8]; int s[8];
        #pragma unroll
        for (int k = 0; k < 8; ++k) {
            p[k] = __shfl(ps0, i + k, 32);
            s[k] = __shfl(s0, i + k, 32);
        }
        if (INFMT == 0) {
            const s8_t* base = (const s8_t*)featv;
            ushort_t u[8];
            #pragma unroll
            for (int k = 0; k < 8; ++k)
                u[k] = ((const ushort_t*)(base + (size_t)s[k] * 64))[sub];
            #pragma unroll
            for (int k = 0; k < 8; ++k) {
                acc0 += p[k] * (float)(s8_t)(u[k] & 0xFF);
                acc1 += p[k] * (float)(s8_t)(u[k] >> 8);
            }
        } else {
            const ushort_t* base = (const ushort_t*)featv;
            uint_t u[8];
            #pragma unroll
            for (int k = 0; k < 8; ++k)
                u[k] = ((const uint_t*)(base + (size_t)s[k] * 64))[sub];
            #pragma unroll
            for (int k = 0; k < 8; ++k) {
                acc0 += p[k] * bf_lo(u[k]);
                acc1 += p[k] * bf_hi(u[k]);
            }
        }
    }
    for (; i + 4 <= head; i += 4) {
        float pA = __shfl(ps0, i, 32), pB = __shfl(ps0, i + 1, 32),
              pC = __shfl(ps0, i + 2, 32), pD = __shfl(ps0, i + 3, 32);
        int sA = __shfl(s0, i, 32), sB = __shfl(s0, i + 1, 32),
            sC = __shfl(s0, i + 2, 32), sD = __shfl(s0, i + 3, 32);
        if (INFMT == 0) {
            const s8_t* base = (const s8_t*)featv;
            ushort_t uA = ((const ushort_t*)(base + (size_t)sA * 64))[sub];
            ushort_t uB = ((const ushort_t*)(base + (size_t)sB * 64))[sub];
            ushort_t uC = ((const ushort_t*)(base + (size_t)sC * 64))[sub];
            ushort_t uD = ((const ushort_t*)(base + (size_t)sD * 64))[sub];
            acc0 += pA * (float)(s8_t)(uA & 0xFF) + pB * (float)(s8_t)(uB & 0xFF)
                  + pC * (float)(s8_t)(uC & 0xFF) + pD * (float)(s8_t)(uD & 0xFF);
            acc1 += pA * (float)(s8_t)(uA >> 8) + pB * (float)(s8_t)(uB >> 8)
                  + pC * (float)(s8_t)(uC >> 8) + pD * (float)(s8_t)(uD >> 8);
        } else {
            const ushort_t* base = (const ushort_t*)featv;
            uint_t vA = ((const uint_t*)(base + (size_t)sA * 64))[sub];
            uint_t vB = ((const uint_t*)(base + (size_t)sB * 64))[sub];
            uint_t vC = ((const uint_t*)(base + (size_t)sC * 64))[sub];
            uint_t vD = ((const uint_t*)(base + (size_t)sD * 64))[sub];
            acc0 += pA * bf_lo(vA) + pB * bf_lo(vB) + pC * bf_lo(vC) + pD * bf_lo(vD);
            acc1 += pA * bf_hi(vA) + pB * bf_hi(vB) + pC * bf_hi(vC) + pD * bf_hi(vD);
        }
    }
    for (; i < head; ++i) {
        float p = __shfl(ps0, i, 32);
        int sN = __shfl(s0, i, 32);
        if (INFMT == 0) {
            ushort_t u = ((const ushort_t*)((const s8_t*)featv + (size_t)sN * 64))[sub];
            acc0 += p * (float)(s8_t)(u & 0xFF);
            acc1 += p * (float)(s8_t)(u >> 8);
        } else {
            uint_t v = ((const uint_t*)((const ushort_t*)featv + (size_t)sN * 64))[sub];
            acc0 += p * bf_lo(v); acc1 += p * bf_hi(v);
        }
    }
    for (i = 32; i < deg; ++i) {  // rare tail (deg>32)
        int sN = csrsrc[start + i];
        float p;
        if (INFMT == 0) {
            float2 es = elscl[sN];
            p = __expf(leaky(es.x + ern) - m) * es.y;
            ushort_t u = ((const ushort_t*)((const s8_t*)featv + (size_t)sN * 64))[sub];
            acc0 += p * (float)(s8_t)(u & 0xFF);
            acc1 += p * (float)(s8_t)(u >> 8);
        } else {
            p = __expf(leaky(elp[sN] + ern) - m);
            uint_t v = ((const uint_t*)((const ushort_t*)featv + (size_t)sN * 64))[sub];
            acc0 += p * bf_lo(v); acc1 += p * bf_hi(v);
        }
    }
    return make_float2(acc0 * inv, acc1 * inv);
}

// ---------------- L1 agg: int8 in, (+b1, relu), int8 out, writes packed elsclB + erB ----
__global__ void agg1_k(const int* __restrict__ off, const int* __restrict__ csrsrc,
                       const float2* __restrict__ elsclA, const float* __restrict__ erA,
                       const s8_t* __restrict__ feat8, const float* __restrict__ bias,
                       s8_t* __restrict__ hA8, const float* __restrict__ val2,
                       const float* __restrict__ var2, float2* __restrict__ elsclB,
                       float* __restrict__ erB, int N) {
    int g = blockIdx.x * blockDim.x + threadIdx.x;
    int node = g >> 5;
    int sub = threadIdx.x & 31;
    if (node >= N) return;
    float2 v = agg_node<0>(off, csrsrc, elsclA, nullptr, erA, feat8, node, sub);
    float2 b2 = ((const float2*)bias)[sub];
    float v0 = fmaxf(v.x + b2.x, 0.f), v1 = fmaxf(v.y + b2.y, 0.f);

    float rm = fmaxf(v0, v1);  // values are >=0 after relu
    for (int o = 16; o; o >>= 1) rm = fmaxf(rm, __shfl_xor(rm, o));
    float qi = (rm > 0.f) ? 127.f / rm : 0.f;
    int q0 = (int)rintf(v0 * qi), q1 = (int)rintf(v1 * qi);
    ((ushort_t*)hA8)[(size_t)node * 32 + sub] =
        (ushort_t)((q0 & 0xFF) | ((q1 & 0xFF) << 8));

    float2 wa = ((const float2*)val2)[sub];
    float2 wb = ((const float2*)var2)[sub];
    float a = v0 * wa.x + v1 * wa.y;
    float b = v0 * wb.x + v1 * wb.y;
    for (int o = 16; o; o >>= 1) { a += __shfl_xor(a, o); b += __shfl_xor(b, o); }
    if (sub == 0) {
        elsclB[node] = make_float2(a, rm * (1.f / 127.f));
        erB[node] = b;
    }
}

// ---------------- merged: L2 agg (-> LDS g) + h3 = relu(g@W2+b2) + feat3 = h3@W3 --------
__global__ void agg2_l23(const int* __restrict__ off, const int* __restrict__ csrsrc,
                         const float2* __restrict__ elsclB, const float* __restrict__ erB,
                         const s8_t* __restrict__ hA8, const ushort_t* __restrict__ Wt2,
                         const float* __restrict__ b2, const ushort_t* __restrict__ Wt3,
                         const float* __restrict__ al3, const float* __restrict__ ar3,
                         ushort_t* __restrict__ feat3, float* __restrict__ el,
                         float* __restrict__ er, int N) {
    __shared__ ushort_t gsh[16 * 64];     // 2 KB, XOR-swizzled (8-col groups ^ row&7)
    __shared__ ushort_t h3s[16 * 128];    // 4 KB, XOR-swizzled
    __shared__ float els[4][16], ers[4][16];
    int tid = threadIdx.x;
    int base = blockIdx.x * 16;

    // phase A: aggregate 16 nodes into swizzled LDS
    #pragma unroll
    for (int r = 0; r < 2; ++r) {
        int row = r * 8 + (tid >> 5);
        int node = base + row;
        int sub = tid & 31;
        float2 v = agg_node<0>(off, csrsrc, elsclB, nullptr, erB, hA8, node, sub);
        int colu = sub ^ ((row & 7) << 2);   // uint-granularity swizzle
        ((uint_t*)gsh)[row * 32 + colu] = ((uint_t)f2bf(v.y) << 16) | f2bf(v.x);
    }
    __syncthreads();

    int wv = tid >> 6, lane = tid & 63;
    int c = lane & 15, kq = lane >> 4;

    // phase B: gemm1 K=64 -> M=128; A row = c from gsh
    bf16x8 a1[2];
    a1[0] = *reinterpret_cast<const bf16x8*>(&gsh[c * 64 + 8 * (kq ^ (c & 7))]);
    a1[1] = *reinterpret_cast<const bf16x8*>(&gsh[c * 64 + 8 * ((4 + kq) ^ (c & 7))]);

    f32x4 acc2[2];
    #pragma unroll
    for (int t = 0; t < 2; ++t) acc2[t] = (f32x4){0.f, 0.f, 0.f, 0.f};
    #pragma unroll
    for (int t = 0; t < 2; ++t) {
        int ct = wv * 2 + t;
        const ushort_t* bptr = Wt2 + (size_t)(ct * 16 + c) * 64 + kq * 8;
        acc2[t] = __builtin_amdgcn_mfma_f32_16x16x32_bf16(
            a1[0], *reinterpret_cast<const bf16x8*>(bptr), acc2[t], 0, 0, 0);
        acc2[t] = __builtin_amdgcn_mfma_f32_16x16x32_bf16(
            a1[1], *reinterpret_cast<const bf16x8*>(bptr + 32), acc2[t], 0, 0, 0);
    }
    #pragma unroll
    for (int t = 0; t < 2; ++t) {
        int ct = wv * 2 + t;
        float bv = b2[ct * 16 + c];
        #pragma unroll
        for (int j = 0; j < 4; ++j) {
            int r = kq * 4 + j;
            float v = fmaxf(acc2[t][j] + bv, 0.f);
            h3s[r * 128 + ((ct * 16 + c) ^ ((r & 7) << 3))] = f2bf(v);
        }
    }
    __syncthreads();

    // phase C: gemm2 K=128 -> M=64; wave wv does col tile wv; A row = c from h3s
    bf16x8 a2[4];
    #pragma unroll
    for (int ki = 0; ki < 4; ++ki)
        a2[ki] = *reinterpret_cast<const bf16x8*>(
            &h3s[c * 128 + 8 * ((ki * 4 + kq) ^ (c & 7))]);

    f32x4 acc3 = (f32x4){0.f, 0.f, 0.f, 0.f};
    const ushort_t* bptr3 = Wt3 + (size_t)(wv * 16 + c) * 128 + kq * 8;
    #pragma unroll
    for (int ki = 0; ki < 4; ++ki) {
        bf16x8 b = *reinterpret_cast<const bf16x8*>(bptr3 + ki * 32);
        acc3 = __builtin_amdgcn_mfma_f32_16x16x32_bf16(a2[ki], b, acc3, 0, 0, 0);
    }

    // epilogue: feat3 store + el3/er3 (cross-wave reduce)
    float alv = al3[wv * 16 + c], arv = ar3[wv * 16 + c];
    float pe[4], pr[4];
    #pragma unroll
    for (int j = 0; j < 4; ++j) {
        float v = acc3[j];
        feat3[(size_t)(base + kq * 4 + j) * 64 + wv * 16 + c] = f2bf(v);
        pe[j] = v * alv;
        pr[j] = v * arv;
    }
    #pragma unroll
    for (int o = 1; o < 16; o <<= 1) {
        #pragma unroll
        for (int j = 0; j < 4; ++j) {
            pe[j] += __shfl_xor(pe[j], o);
            pr[j] += __shfl_xor(pr[j], o);
        }
    }
    if (c == 0) {
        #pragma unroll
        for (int j = 0; j < 4; ++j) { els[wv][kq * 4 + j] = pe[j]; ers[wv][kq * 4 + j] = pr[j]; }
    }
    __syncthreads();
    if (tid < 16) {
        el[base + tid] = els[0][tid] + els[1][tid] + els[2][tid] + els[3][tid];
        er[base + tid] = ers[0][tid] + ers[1][tid] + ers[2][tid] + ers[3][tid];
    }
}

// ---------------- L3 agg: bf16 in, (+b3), fp32 out + link-pred partials ----------------
__global__ void agg3_k(const int* __restrict__ off, const int* __restrict__ csrsrc,
                       const float* __restrict__ elA, const float* __restrict__ erA,
                       const ushort_t* __restrict__ f3bf, const float* __restrict__ bias,
                       float* __restrict__ outh, const float* __restrict__ lpW,
                       float* __restrict__ s1, float* __restrict__ s2, int N) {
    int g = blockIdx.x * blockDim.x + threadIdx.x;
    int node = g >> 5;
    int sub = threadIdx.x & 31;
    if (node >= N) return;
    float2 v = agg_node<1>(off, csrsrc, nullptr, elA, erA, f3bf, node, sub);
    float2 b2 = ((const float2*)bias)[sub];
    float v0 = v.x + b2.x, v1 = v.y + b2.y;
    ((float2*)outh)[(size_t)node * 32 + sub] = make_float2(v0, v1);

    float2 wa = ((const float2*)lpW)[sub];
    float2 wb = ((const float2*)(lpW + 64))[sub];
    float a = v0 * wa.x + v1 * wa.y;
    float b = v0 * wb.x + v1 * wb.y;
    for (int o = 16; o; o >>= 1) { a += __shfl_xor(a, o); b += __shfl_xor(b, o); }
    if (sub == 0) { s1[node] = a; s2[node] = b; }
}

// ---------------- MFMA GEMM core (K=128, M=64), A from fp32 X, int8 feat out + packed
// elscl, fused el/er epilogue ----------------
__device__ __forceinline__ void gemm64_f32core(const float* __restrict__ X,
                                               const ushort_t* __restrict__ Wt,
                                               const float* __restrict__ al,
                                               const float* __restrict__ ar,
                                               s8_t* __restrict__ feat8,
                                               float2* __restrict__ elscl,
                                               float* __restrict__ er,
                                               int N, int blk, int tid) {
    constexpr int CT = 4, KI = 4;
    int wv = tid >> 6, lane = tid & 63;
    int c = lane & 15, kq = lane >> 4;
    int n0 = blk * 64 + wv * 16;
    if (n0 >= N) return;

    const float* aptr = X + (size_t)(n0 + c) * 128 + kq * 8;
    bf16x8 a[KI];
    #pragma unroll
    for (int ki = 0; ki < KI; ++ki) {
        float4 f0 = *reinterpret_cast<const float4*>(aptr + ki * 32);
        float4 f1 = *reinterpret_cast<const float4*>(aptr + ki * 32 + 4);
        union { bf16x8 v; ushort_t u[8]; } pk;
        pk.u[0] = f2bf(f0.x); pk.u[1] = f2bf(f0.y); pk.u[2] = f2bf(f0.z); pk.u[3] = f2bf(f0.w);
        pk.u[4] = f2bf(f1.x); pk.u[5] = f2bf(f1.y); pk.u[6] = f2bf(f1.z); pk.u[7] = f2bf(f1.w);
        a[ki] = pk.v;
    }

    f32x4 acc[CT];
    #pragma unroll
    for (int ct = 0; ct < CT; ++ct) acc[ct] = (f32x4){0.f, 0.f, 0.f, 0.f};

    #pragma unroll
    for (int ct = 0; ct < CT; ++ct) {
        const ushort_t* bptr = Wt + (size_t)(ct * 16 + c) * 128 + kq * 8;
        #pragma unroll
        for (int ki = 0; ki < KI; ++ki) {
            bf16x8 b = *reinterpret_cast<const bf16x8*>(bptr + ki * 32);
            acc[ct] = __builtin_amdgcn_mfma_f32_16x16x32_bf16(a[ki], b, acc[ct], 0, 0, 0);
        }
    }

    float pe[4] = {0.f, 0.f, 0.f, 0.f}, pr[4] = {0.f, 0.f, 0.f, 0.f};
    float pm[4] = {0.f, 0.f, 0.f, 0.f};
    #pragma unroll
    for (int ct = 0; ct < CT; ++ct) {
        float alv = al[ct * 16 + c], arv = ar[ct * 16 + c];
        #pragma unroll
        for (int j = 0; j < 4; ++j) {
            float v = acc[ct][j];
            pe[j] += v * alv;
            pr[j] += v * arv;
            pm[j] = fmaxf(pm[j], fabsf(v));
        }
    }
    #pragma unroll
    for (int o = 1; o < 16; o <<= 1) {
        #pragma unroll
        for (int j = 0; j < 4; ++j) {
            pe[j] += __shfl_xor(pe[j], o);
            pr[j] += __shfl_xor(pr[j], o);
            pm[j] = fmaxf(pm[j], __shfl_xor(pm[j], o));
        }
    }
    #pragma unroll
    for (int j = 0; j < 4; ++j) {
        float qi = (pm[j] > 0.f) ? 127.f / pm[j] : 0.f;
        int row = n0 + kq * 4 + j;
        #pragma unroll
        for (int ct = 0; ct < CT; ++ct) {
            int q = (int)rintf(acc[ct][j] * qi);
            feat8[(size_t)row * 64 + ct * 16 + c] = (s8_t)q;
        }
    }
    if (c == 0) {
        #pragma unroll
        for (int j = 0; j < 4; ++j) {
            elscl[n0 + kq * 4 + j] = make_float2(pe[j], pm[j] * (1.f / 127.f));
            er[n0 + kq * 4 + j] = pr[j];
        }
    }
}

// ---------------- bucket_csr + L1 gemm fused ----------------
__global__ void csr_gemm1(const uint_t* __restrict__ pairbuf, const uint_t* __restrict__ bucketbase,
                          int* __restrict__ off, int* __restrict__ csrsrc,
                          const float* __restrict__ X, const ushort_t* __restrict__ Wt1,
                          const float* __restrict__ al1, const float* __restrict__ ar1,
                          s8_t* __restrict__ feat8, float2* __restrict__ elsclA,
                          float* __restrict__ erA, int N) {
    __shared__ uint_t cnt[256];
    __shared__ uint_t ws4[4];
    int tid = threadIdx.x;
    if (blockIdx.x >= NBKT) {  // gemm part
        gemm64_f32core(X, Wt1, al1, ar1, feat8, elsclA, erA, N, blockIdx.x - NBKT, tid);
        return;
    }
    // bucket_csr part
    int b = blockIdx.x;
    uint_t eb0 = bucketbase[b], m = bucketbase[b + 1] - eb0;
    cnt[tid] = 0;
    __syncthreads();
    for (uint_t i = tid; i < m; i += 256)
        atomicAdd(&cnt[pairbuf[eb0 + i] >> 16], 1u);
    __syncthreads();
    uint_t v = cnt[tid];
    int lane = tid & 63, w = tid >> 6;
    uint_t sc = v;
    for (int o = 1; o < 64; o <<= 1) {
        uint_t x = __shfl_up(sc, o);
        if (lane >= o) sc += x;
    }
    if (lane == 63) ws4[w] = sc;
    __syncthreads();
    if (tid == 0) { uint_t r = 0; for (int i = 0; i < 4; ++i) { uint_t tmp = ws4[i]; ws4[i] = r; r += tmp; } }
    __syncthreads();
    uint_t excl = ws4[w] + sc - v;
    int node = b * 256 + tid;
    if (node < NN) off[node] = (int)(eb0 + excl);
    if (b == 0 && tid == 0) off[NN] = NE;
    __syncthreads();
    cnt[tid] = eb0 + excl;  // reuse as cursor
    __syncthreads();
    for (uint_t i = tid; i < m; i += 256) {
        uint_t p = pairbuf[eb0 + i];
        uint_t pos = atomicAdd(&cnt[p >> 16], 1u);
        csrsrc[pos] = (int)(p & 0xFFFFu);
    }
}

// ---------------- scores: 4 edges per thread, both lists in one launch ----------------
__global__ void scores4_k(const int4* __restrict__ s4, const int4* __restrict__ d4,
                          const int4* __restrict__ ns4, const int4* __restrict__ nd4,
                          const float* __restrict__ s1, const float* __restrict__ s2,
                          const float* __restrict__ lpb,
                          float4* __restrict__ outp, float4* __restrict__ outn, int E4) {
    int i = blockIdx.x * blockDim.x + threadIdx.x;
    float cc = lpb[0];
    if (i < E4) {
        int4 s = s4[i], d = d4[i];
        outp[i] = make_float4(s1[s.x] + s2[d.x] + cc, s1[s.y] + s2[d.y] + cc,
                              s1[s.z] + s2[d.z] + cc, s1[s.w] + s2[d.w] + cc);
    } else if (i < 2 * E4) {
        int j = i - E4;
        int4 s = ns4[j], d = nd4[j];
        outn[j] = make_float4(s1[s.x] + s2[d.x] + cc, s1[s.y] + s2[d.y] + cc,
                              s1[s.z] + s2[d.z] + cc, s1[s.w] + s2[d.w] + cc);
    }
}

// ---------------- driver ----------------

struct Scratch {
    ushort_t* wt1; ushort_t* wt2; ushort_t* wt3;
    s8_t* feat8; s8_t* hA8;
    ushort_t* f3bf;
    float2* elsclA; float2* elsclB;
    float* erA; float* erB;
    float* elL3; float* erL3;
    float* val2; float* var2; float* s1; float* s2;
    int* off; int* csrsrc; uint_t* gh; uint_t* bucketbase;
    uint_t* pairbuf;
};

extern "C" void kernel_launch(void* const* d_in, const int* in_sizes, int n_in,
                              void* d_out, int out_size, void* d_ws, size_t ws_size,
                              hipStream_t stream) {
    const float* x   = (const float*)d_in[0];
    const float* W1  = (const float*)d_in[1];
    const float* al1 = (const float*)d_in[2];
    const float* ar1 = (const float*)d_in[3];
    const float* b1  = (const float*)d_in[4];
    const float* W2  = (const float*)d_in[5];
    const float* al2 = (const float*)d_in[6];
    const float* ar2 = (const float*)d_in[7];
    const float* b2  = (const float*)d_in[8];
    const float* W3  = (const float*)d_in[9];
    const float* al3 = (const float*)d_in[10];
    const float* ar3 = (const float*)d_in[11];
    const float* b3  = (const float*)d_in[12];
    const float* lpW = (const float*)d_in[13];
    const float* lpb = (const float*)d_in[14];
    const int* src  = (const int*)d_in[15];
    const int* dst  = (const int*)d_in[16];
    const int* nsrc = (const int*)d_in[17];
    const int* ndst = (const int*)d_in[18];

    char* w = (char*)d_ws;
    Scratch S;
    S.feat8      = (s8_t*)w;     w += (size_t)NN * 64;
    S.hA8        = (s8_t*)w;     w += (size_t)NN * 64;
    S.f3bf       = (ushort_t*)w; w += (size_t)NN * 64 * 2;
    S.elsclA     = (float2*)w;   w += (size_t)NN * 8;
    S.elsclB     = (float2*)w;   w += (size_t)NN * 8;
    S.erA        = (float*)w;    w += (size_t)NN * 4;
    S.erB        = (float*)w;    w += (size_t)NN * 4;
    S.elL3       = (float*)w;    w += (size_t)NN * 4;
    S.erL3       = (float*)w;    w += (size_t)NN * 4;
    S.wt1        = (ushort_t*)w; w += 128 * 64 * 2;
    S.wt2        = (ushort_t*)w; w += 64 * 128 * 2;
    S.wt3        = (ushort_t*)w; w += 128 * 64 * 2;
    S.val2       = (float*)w;    w += 64 * 4;
    S.var2       = (float*)w;    w += 64 * 4;
    S.s1         = (float*)w;    w += (size_t)NN * 4;
    S.s2         = (float*)w;    w += (size_t)NN * 4;
    S.off        = (int*)w;      w += (size_t)(NN + 1) * 4;
    S.csrsrc     = (int*)w;      w += (size_t)NE * 4;
    S.gh         = (uint_t*)w;   w += (size_t)NBKT * NT * 4;
    S.bucketbase = (uint_t*)w;   w += (size_t)(NBKT + 1) * 4;
    S.pairbuf    = (uint_t*)w;   w += (size_t)NE * 4;

    const int GEMM_GRID = (NN + 63) / 64;      // 782
    const int AGG_GRID = (NN * 32 + 255) / 256;

    // 1) histogram + weight prep
    prep_hist<<<NT + WBLK + 1, 256, 0, stream>>>(
        W1, W2, W3, S.wt1, S.wt2, S.wt3, al2, ar2, S.val2, S.var2, dst, S.gh);
    // 2) scan
    scan_gh<<<1, 1024, 0, stream>>>(S.gh, S.bucketbase);
    // 3) bucket-scatter pairs
    part_scatter<<<NT, 256, 0, stream>>>(src, dst, S.gh, S.bucketbase, S.pairbuf);
    // 4) CSR finalize + L1 gemm (int8 feat + packed elsclA)
    csr_gemm1<<<NBKT + GEMM_GRID, 256, 0, stream>>>(
        S.pairbuf, S.bucketbase, S.off, S.csrsrc,
        x, S.wt1, al1, ar1, S.feat8, S.elsclA, S.erA, NN);

    float* out_h   = (float*)d_out;
    float* out_pos = out_h + (size_t)NN * 64;
    float* out_neg = out_pos + NE;

    // 5) L1 agg -> hA8 + packed elsclB/erB
    agg1_k<<<AGG_GRID, 256, 0, stream>>>(
        S.off, S.csrsrc, S.elsclA, S.erA, S.feat8, b1, S.hA8,
        S.val2, S.var2, S.elsclB, S.erB, NN);
    // 6) merged L2 agg + both GEMMs -> feat3 + el3/er3
    agg2_l23<<<NN / 16, 256, 0, stream>>>(
        S.off, S.csrsrc, S.elsclB, S.erB, S.hA8, S.wt2, b2, S.wt3, al3, ar3,
        S.f3bf, S.elL3, S.erL3, NN);
    // 7) L3 agg -> d_out h + s1/s2
    agg3_k<<<AGG_GRID, 256, 0, stream>>>(
        S.off, S.csrsrc, S.elL3, S.erL3, S.f3bf, b3, out_h, lpW, S.s1, S.s2, NN);
    // 8) scores
    const int E4 = NE / 4;
    scores4_k<<<(2 * E4 + 255) / 256, 256, 0, stream>>>(
        (const int4*)src, (const int4*)dst, (const int4*)nsrc, (const int4*)ndst,
        S.s1, S.s2, lpb, (float4*)out_pos, (float4*)out_neg, E4);
}